// Round 8
// baseline (4467.915 us; speedup 1.0000x reference)
//
#include <hip/hip_runtime.h>
#include <math.h>

// ---------------------------------------------------------------------------
#define D 768
#define NPARA 32
#define LPARA 512
#define LQ 32
#define NENT 10000
#define MMENT 30000
#define NPAIR 20000
#define NSTEP 3
#define CHUNK 10000

using bf16x8 = __attribute__((ext_vector_type(8))) short;
using f32x4  = __attribute__((ext_vector_type(4))) float;

__device__ __forceinline__ float geluf(float x) {
    return 0.5f * x * (1.0f + erff(x * 0.70710678118654752f));
}
__device__ __forceinline__ float bf2f(ushort h) {
    union { unsigned u; float f; } v; v.u = ((unsigned)h) << 16; return v.f;
}
__device__ __forceinline__ ushort bfhi(float x) {
    union { float f; unsigned u; } v; v.f = x; return (ushort)(v.u >> 16);
}
__device__ __forceinline__ void bfsplit(float x, ushort& h, ushort& l) {
    h = bfhi(x);
    l = bfhi(x - bf2f(h));
}

// ---------------------------------------------------------------------------
// Split-bf16 MFMA GEMM, A-only LDS (32KB) + direct-global B fragments +
// register prefetch of next A tile (MODE 0/1). Band-major XCD swizzle.
// MODE 0: A = hi/lo bf16 planes [M][K]
// MODE 1: A row r = concat(para[p,t1,:], para[p,t2,:]) fp32 gather, K=1536
// MODE 2: A row r, sections {S, O, S*O} from feat planes, K=2304 (folded W1)
// B: pre-transposed weight planes WT[N][K] (linear, not swizzled).
// OUTP 0: fp32 C; 1: hi/lo bf16 planes.
// ---------------------------------------------------------------------------
#define BM 128
#define BN 128

__device__ __forceinline__ int ldso(int row, int kb) {   // ushort index
    return row * 64 + (((kb) ^ ((row & 7) << 4)) >> 1);
}

template <int MODE, int ACT, int OUTP>
__global__ __launch_bounds__(256, 3) void gemm_m(
    const ushort* __restrict__ Ah, const ushort* __restrict__ Al,
    const float* __restrict__ para, const int* __restrict__ ppos, int c1, int c2,
    const ushort* __restrict__ Sh, const ushort* __restrict__ Sl,
    const ushort* __restrict__ Oh, const ushort* __restrict__ Ol,
    const ushort* __restrict__ Bh, const ushort* __restrict__ Bl,
    const float* __restrict__ bias,
    float* __restrict__ Cf, ushort* __restrict__ Ch, ushort* __restrict__ Cl,
    int M, int N, int K, int nby)
{
    __shared__ ushort sAh[BM * 64], sAl[BM * 64];   // 32 KB

    // band-major bijective XCD swizzle (m204)
    const int nwg = gridDim.x;
    const int q = nwg >> 3, r = nwg & 7;
    const int xcd = blockIdx.x & 7, idx = blockIdx.x >> 3;
    const int wgid = (xcd < r) ? xcd * (q + 1) + idx
                               : r * (q + 1) + (xcd - r) * q + idx;
    const int m0 = (wgid / nby) * BM;
    const int n0 = (wgid % nby) * BN;

    const int tid = threadIdx.x;
    const int lane = tid & 63;
    const int wv = tid >> 6;
    const int wr = (wv >> 1) * 64;
    const int wc = (wv & 1) * 64;
    const int ln = lane & 15;
    const int kg = lane >> 4;

    f32x4 acc[4][4];
#pragma unroll
    for (int i = 0; i < 4; ++i)
#pragma unroll
        for (int j = 0; j < 4; ++j)
#pragma unroll
            for (int e = 0; e < 4; ++e) acc[i][j][e] = 0.0f;

    const int srow = tid & 127;
    const int shalf = tid >> 7;
    const int gm = m0 + srow;
    const bool ok = gm < M;

    // MODE 1: hoist gather bases once
    int baseL = 0, baseR = 0;
    if (MODE == 1 && ok) {
        int p = ppos[gm * 5];
        baseL = (p * LPARA + ppos[gm * 5 + c1]) * D;
        baseR = (p * LPARA + ppos[gm * 5 + c2]) * D;
    }

    bf16x8 pa[8];    // MODE 0 prefetch: [0..3]=hi, [4..7]=lo
    float4 pf[8];    // MODE 1 prefetch: 32 fp32

    // ---- prefetch tile 0 ----
    if (MODE == 0) {
#pragma unroll
        for (int j = 0; j < 4; ++j) {
            int kc = shalf * 32 + j * 8;
            if (ok) {
                pa[j]     = *(const bf16x8*)(Ah + (size_t)gm * K + kc);
                pa[4 + j] = *(const bf16x8*)(Al + (size_t)gm * K + kc);
            } else {
#pragma unroll
                for (int z = 0; z < 8; ++z) { pa[j][z] = 0; pa[4 + j][z] = 0; }
            }
        }
    } else if (MODE == 1) {
#pragma unroll
        for (int j = 0; j < 8; ++j) {
            int kc = shalf * 32 + j * 4;
            pf[j] = ok ? *(const float4*)(para + baseL + kc)
                       : make_float4(0.f, 0.f, 0.f, 0.f);
        }
    }

    for (int kt = 0; kt < K; kt += 64) {
        if (kt > 0) __syncthreads();   // protect LDS from overwrite

        // ---- store staged tile into LDS (swizzled) ----
        if (MODE == 0) {
#pragma unroll
            for (int j = 0; j < 4; ++j) {
                int kc = shalf * 32 + j * 8;
                int o = ldso(srow, kc * 2);
                *(bf16x8*)&sAh[o] = pa[j];
                *(bf16x8*)&sAl[o] = pa[4 + j];
            }
        } else if (MODE == 1) {
#pragma unroll
            for (int j = 0; j < 8; ++j) {
                int kc = shalf * 32 + j * 4;
                ushort4 h, l;
                bfsplit(pf[j].x, h.x, l.x); bfsplit(pf[j].y, h.y, l.y);
                bfsplit(pf[j].z, h.z, l.z); bfsplit(pf[j].w, h.w, l.w);
                int o = ldso(srow, kc * 2);
                *(ushort4*)&sAh[o] = h;
                *(ushort4*)&sAl[o] = l;
            }
        } else {  // MODE 2: synchronous stage {S, O, S*O}
            const int sec = kt / D;
            const int r0 = kt - sec * D;
            const size_t rb = (size_t)gm * D + r0;
#pragma unroll
            for (int j = 0; j < 8; ++j) {
                int kc = shalf * 32 + j * 4;
                ushort4 h, l;
                if (ok) {
                    float val[4];
                    if (sec == 0) {
                        ushort4 a = *(const ushort4*)(Sh + rb + kc);
                        ushort4 b = *(const ushort4*)(Sl + rb + kc);
                        val[0] = bf2f(a.x) + bf2f(b.x); val[1] = bf2f(a.y) + bf2f(b.y);
                        val[2] = bf2f(a.z) + bf2f(b.z); val[3] = bf2f(a.w) + bf2f(b.w);
                    } else if (sec == 1) {
                        ushort4 c = *(const ushort4*)(Oh + rb + kc);
                        ushort4 d = *(const ushort4*)(Ol + rb + kc);
                        val[0] = bf2f(c.x) + bf2f(d.x); val[1] = bf2f(c.y) + bf2f(d.y);
                        val[2] = bf2f(c.z) + bf2f(d.z); val[3] = bf2f(c.w) + bf2f(d.w);
                    } else {
                        ushort4 a = *(const ushort4*)(Sh + rb + kc);
                        ushort4 b = *(const ushort4*)(Sl + rb + kc);
                        ushort4 c = *(const ushort4*)(Oh + rb + kc);
                        ushort4 d = *(const ushort4*)(Ol + rb + kc);
                        val[0] = (bf2f(a.x) + bf2f(b.x)) * (bf2f(c.x) + bf2f(d.x));
                        val[1] = (bf2f(a.y) + bf2f(b.y)) * (bf2f(c.y) + bf2f(d.y));
                        val[2] = (bf2f(a.z) + bf2f(b.z)) * (bf2f(c.z) + bf2f(d.z));
                        val[3] = (bf2f(a.w) + bf2f(b.w)) * (bf2f(c.w) + bf2f(d.w));
                    }
                    bfsplit(val[0], h.x, l.x); bfsplit(val[1], h.y, l.y);
                    bfsplit(val[2], h.z, l.z); bfsplit(val[3], h.w, l.w);
                } else {
                    h.x = h.y = h.z = h.w = 0; l = h;
                }
                int o = ldso(srow, kc * 2);
                *(ushort4*)&sAh[o] = h;
                *(ushort4*)&sAl[o] = l;
            }
        }
        __syncthreads();

        // ---- prefetch next tile (MODE 0/1): latency hides under compute ----
        const int ktn = kt + 64;
        if (MODE == 0 && ktn < K) {
#pragma unroll
            for (int j = 0; j < 4; ++j) {
                int kc = shalf * 32 + j * 8;
                if (ok) {
                    pa[j]     = *(const bf16x8*)(Ah + (size_t)gm * K + ktn + kc);
                    pa[4 + j] = *(const bf16x8*)(Al + (size_t)gm * K + ktn + kc);
                }
            }
        } else if (MODE == 1 && ktn < K) {
            const int gb = (ktn < D) ? (baseL + ktn) : (baseR + ktn - D);
#pragma unroll
            for (int j = 0; j < 8; ++j) {
                int kc = shalf * 32 + j * 4;
                if (ok) pf[j] = *(const float4*)(para + gb + kc);
            }
        }

        // ---- compute: B fragments direct from global, A from LDS ----
#pragma unroll
        for (int ks = 0; ks < 2; ++ks) {
            bf16x8 fbh[4], fbl[4];
#pragma unroll
            for (int ni = 0; ni < 4; ++ni) {
                const size_t brow = (size_t)(n0 + wc + ni * 16 + ln) * K
                                  + kt + ks * 32 + kg * 8;
                fbh[ni] = *(const bf16x8*)(Bh + brow);
                fbl[ni] = *(const bf16x8*)(Bl + brow);
            }
#pragma unroll
            for (int mi = 0; mi < 4; ++mi) {
                int rr = wr + mi * 16 + ln;
                int o = ldso(rr, ks * 64 + kg * 16);
                bf16x8 fah = *(const bf16x8*)&sAh[o];
                bf16x8 fal = *(const bf16x8*)&sAl[o];
#pragma unroll
                for (int ni = 0; ni < 4; ++ni) {
                    acc[mi][ni] = __builtin_amdgcn_mfma_f32_16x16x32_bf16(
                        fah, fbh[ni], acc[mi][ni], 0, 0, 0);
                    acc[mi][ni] = __builtin_amdgcn_mfma_f32_16x16x32_bf16(
                        fah, fbl[ni], acc[mi][ni], 0, 0, 0);
                    acc[mi][ni] = __builtin_amdgcn_mfma_f32_16x16x32_bf16(
                        fal, fbh[ni], acc[mi][ni], 0, 0, 0);
                }
            }
        }
    }

    // ---- epilogue: row = (lane>>4)*4+reg, col = lane&15 ----
#pragma unroll
    for (int mi = 0; mi < 4; ++mi)
#pragma unroll
        for (int ni = 0; ni < 4; ++ni) {
            int col = n0 + wc + ni * 16 + ln;
            f32x4 a = acc[mi][ni];
#pragma unroll
            for (int j = 0; j < 4; ++j) {
                int row = m0 + wr + mi * 16 + kg * 4 + j;
                if (row < M) {
                    float v = a[j] + bias[col];
                    if (ACT == 1) v = geluf(v);
                    if (OUTP == 0) {
                        Cf[(size_t)row * N + col] = v;
                    } else {
                        ushort h, l;
                        bfsplit(v, h, l);
                        Ch[(size_t)row * N + col] = h;
                        Cl[(size_t)row * N + col] = l;
                    }
                }
            }
        }
}

// ---------------------------------------------------------------------------
__global__ __launch_bounds__(256) void k_wt(const float* __restrict__ W,
                                            ushort* __restrict__ WTh,
                                            ushort* __restrict__ WTl, int K, int N)
{
    __shared__ float t[32][33];
    const int k0 = blockIdx.x * 32, n0 = blockIdx.y * 32;
    const int c = threadIdx.x & 31, r8 = threadIdx.x >> 5;
#pragma unroll
    for (int i = 0; i < 4; ++i) {
        int r = r8 + i * 8;
        t[r][c] = W[(size_t)(k0 + r) * N + n0 + c];
    }
    __syncthreads();
#pragma unroll
    for (int i = 0; i < 4; ++i) {
        int r = r8 + i * 8;
        float v = t[c][r];
        ushort h, l;
        bfsplit(v, h, l);
        WTh[(size_t)(n0 + r) * K + k0 + c] = h;
        WTl[(size_t)(n0 + r) * K + k0 + c] = l;
    }
}

// folded pair W1: Wf[2304][768] from pW1[3072][768]
__global__ void k_fold(const float* __restrict__ pW1, float* __restrict__ Wf, int n)
{
    int i = blockIdx.x * blockDim.x + threadIdx.x;
    if (i >= n) return;
    int row = i / D;
    float v;
    if (row < D)            v = pW1[i] - pW1[i + 1536 * D];
    else if (row < 2 * D)   v = pW1[i] + pW1[i + 768 * D];
    else                    v = pW1[i + 768 * D];
    Wf[i] = v;
}

__global__ __launch_bounds__(256) void k_entmean(
    const float* __restrict__ para, const int* __restrict__ mpos,
    const int* __restrict__ mid, int M, ushort* __restrict__ oh, ushort* __restrict__ ol)
{
    __shared__ int sb[2];
    const int e = blockIdx.x;
    if (threadIdx.x < 2) {
        int target = e + threadIdx.x;
        int lo = 0, hi = M;
        while (lo < hi) {
            int md = (lo + hi) >> 1;
            if (mid[md] < target) lo = md + 1; else hi = md;
        }
        sb[threadIdx.x] = lo;
    }
    __syncthreads();
    const int lo = sb[0], hi = sb[1];
    const int tid = threadIdx.x;
    float a0 = 0, a1 = 0, a2 = 0, b0 = 0, b1 = 0, b2 = 0;
    for (int m = lo; m < hi; ++m) {
        int p = mpos[m * 3], t1 = mpos[m * 3 + 1], t2 = mpos[m * 3 + 2];
        const float* L = para + (size_t)(p * LPARA + t1) * D;
        const float* R = para + (size_t)(p * LPARA + t2) * D;
        a0 += L[tid]; a1 += L[tid + 256]; a2 += L[tid + 512];
        b0 += R[tid]; b1 += R[tid + 256]; b2 += R[tid + 512];
    }
    const float inv = (hi > lo) ? 1.0f / (float)(hi - lo) : 0.0f;
    size_t base = (size_t)e * (2 * D);
    float vals[6] = { a0 * inv, a1 * inv, a2 * inv, b0 * inv, b1 * inv, b2 * inv };
    int offs[6] = { tid, tid + 256, tid + 512, D + tid, D + tid + 256, D + tid + 512 };
#pragma unroll
    for (int i = 0; i < 6; ++i) {
        ushort h, l;
        bfsplit(vals[i], h, l);
        oh[base + offs[i]] = h;
        ol[base + offs[i]] = l;
    }
}

__global__ void k_vecmat(const float* __restrict__ x, const float* __restrict__ W,
                         const float* __restrict__ b, float* __restrict__ out,
                         int K, int N, int act)
{
    int j = blockIdx.x * blockDim.x + threadIdx.x;
    if (j >= N) return;
    float s = 0.0f;
    for (int k = 0; k < K; ++k) s = fmaf(x[k], W[(size_t)k * N + j], s);
    s += b[j];
    if (act) s = geluf(s);
    out[j] = s;
}

__global__ void k_ctx(const float* __restrict__ cq, const float* __restrict__ qwh,
                      float* __restrict__ ctx)
{
    __shared__ float red[256];
    __shared__ float dist[LQ];
    const int tid = threadIdx.x;
    const int l = tid >> 3, part = tid & 7;
    float s = 0.0f;
    for (int d = part; d < D; d += 8) s += cq[d] * qwh[l * D + d];
    red[tid] = s;
    __syncthreads();
    if (part == 0) {
        float v = 0;
        for (int i = 0; i < 8; ++i) v += red[l * 8 + i];
        dist[l] = v;
    }
    __syncthreads();
    if (tid == 0) {
        float mx = -1e30f;
        for (int i = 0; i < LQ; ++i) mx = fmaxf(mx, dist[i]);
        float sm = 0;
        for (int i = 0; i < LQ; ++i) { float e = expf(dist[i] - mx); dist[i] = e; sm += e; }
        float inv = 1.0f / sm;
        for (int i = 0; i < LQ; ++i) dist[i] *= inv;
    }
    __syncthreads();
    for (int d = tid; d < D; d += 256) {
        float v = 0;
#pragma unroll
        for (int l2 = 0; l2 < LQ; ++l2) v += dist[l2] * qwh[l2 * D + d];
        ctx[d] = v + cq[d];
    }
}

__global__ void k_scalew(const float* __restrict__ ctx, const float* __restrict__ w1,
                         float* __restrict__ o, int n)
{
    int i = blockIdx.x * 256 + threadIdx.x;
    if (i < n) o[i] = ctx[i >> 8] * w1[i];
}

template <int PAIRMODE>
__global__ void k_rowdot(const float* __restrict__ H, const float* __restrict__ w2,
                         const float* __restrict__ sb2, int Nr,
                         float* __restrict__ simout,
                         const float* __restrict__ laste, const int* __restrict__ so,
                         float* __restrict__ newe)
{
    int r = blockIdx.x * 4 + (threadIdx.x >> 6);
    int lane = threadIdx.x & 63;
    if (r >= Nr) return;
    float s = 0.0f;
#pragma unroll
    for (int i = 0; i < 4; ++i)
        s += H[(size_t)r * 256 + lane + i * 64] * w2[lane + i * 64];
    for (int off = 32; off > 0; off >>= 1) s += __shfl_down(s, off, 64);
    if (lane == 0) {
        s += sb2[0];
        if (PAIRMODE == 0) {
            simout[r] = s;
        } else {
            float p = 1.0f / (1.0f + expf(-s));
            float v = laste[so[r * 2]] * p;
            atomicAdd(&newe[so[r * 2 + 1]], v);
        }
    }
}

__global__ void k_softmax(const float* __restrict__ sim, float* __restrict__ outp, int n)
{
    __shared__ float red[256];
    __shared__ float s_mx, s_sum;
    const int tid = threadIdx.x;
    float mx = -1e30f;
    for (int i = tid; i < n; i += 256) mx = fmaxf(mx, sim[i]);
    red[tid] = mx; __syncthreads();
    for (int off = 128; off > 0; off >>= 1) {
        if (tid < off) red[tid] = fmaxf(red[tid], red[tid + off]);
        __syncthreads();
    }
    if (tid == 0) s_mx = red[0];
    __syncthreads();
    const float mxv = s_mx;
    float sum = 0;
    for (int i = tid; i < n; i += 256) sum += expf(sim[i] - mxv);
    red[tid] = sum; __syncthreads();
    for (int off = 128; off > 0; off >>= 1) {
        if (tid < off) red[tid] += red[tid + off];
        __syncthreads();
    }
    if (tid == 0) s_sum = red[0];
    __syncthreads();
    const float inv = 1.0f / s_sum;
    for (int i = tid; i < n; i += 256) {
        float v = expf(sim[i] - mxv) * inv;
        outp[i] = v / fmaxf(v, 1.0f);
    }
}

__global__ void k_zero(float* p, int n)
{
    int i = blockIdx.x * blockDim.x + threadIdx.x;
    if (i < n) p[i] = 0.0f;
}

__global__ void k_clampstore(const float* __restrict__ ne, float* __restrict__ outp, int n)
{
    int i = blockIdx.x * blockDim.x + threadIdx.x;
    if (i < n) { float v = ne[i]; outp[i] = v / fmaxf(v, 1.0f); }
}

__global__ void k_final(const float* __restrict__ probs, const float* __restrict__ hlog,
                        float* __restrict__ out, int n)
{
    int i = blockIdx.x * blockDim.x + threadIdx.x;
    if (i >= n) return;
    float l0 = hlog[0], l1 = hlog[1], l2 = hlog[2];
    float m = fmaxf(l0, fmaxf(l1, l2));
    float e0 = expf(l0 - m), e1 = expf(l1 - m), e2 = expf(l2 - m);
    float inv = 1.0f / (e0 + e1 + e2);
    out[i] = (e0 * probs[i] + e1 * probs[n + i] + e2 * probs[2 * n + i]) * inv;
}

// ---------------------------------------------------------------------------
extern "C" void kernel_launch(void* const* d_in, const int* in_sizes, int n_in,
                              void* d_out, int out_size, void* d_ws, size_t ws_size,
                              hipStream_t stream)
{
    const size_t WS_NEED = 142790016;  // 136.2 MiB
    if (ws_size < WS_NEED) return;

    const float* para  = (const float*)d_in[0];
    const float* q     = (const float*)d_in[1];
    const float* qwh   = (const float*)d_in[2];
    const float* stW1  = (const float*)d_in[3];
    const float* stb1  = (const float*)d_in[4];
    const float* stW2  = (const float*)d_in[5];
    const float* stb2  = (const float*)d_in[6];
    const float* mW1   = (const float*)d_in[7];
    const float* mb1   = (const float*)d_in[8];
    const float* mW2   = (const float*)d_in[9];
    const float* mb2   = (const float*)d_in[10];
    const float* pW1   = (const float*)d_in[11];
    const float* pb1   = (const float*)d_in[12];
    const float* pW2   = (const float*)d_in[13];
    const float* pb2   = (const float*)d_in[14];
    const float* simW1 = (const float*)d_in[15];
    const float* simb1 = (const float*)d_in[16];
    const float* simW2 = (const float*)d_in[17];
    const float* simb2 = (const float*)d_in[18];
    const float* hW1   = (const float*)d_in[19];
    const float* hb1   = (const float*)d_in[20];
    const float* hW2   = (const float*)d_in[21];
    const float* hb2   = (const float*)d_in[22];
    const int*   mpos  = (const int*)d_in[23];
    const int*   mid   = (const int*)d_in[24];
    const int*   ppos  = (const int*)d_in[25];
    const int*   pso   = (const int*)d_in[26];

    // ---- workspace layout ----
    ushort* P1h  = (ushort*)d_ws;          // 15,360,000 (EM -> sub_feat -> pair_emb)
    ushort* P1l  = P1h  + 15360000;
    ushort* HIDh = P1l  + 15360000;        //  7,680,000 (hidden; H256 fp32 overlay)
    ushort* HIDl = HIDh + 7680000;
    ushort* Eh   = HIDl + 7680000;         //  7,680,000 (Wfold tmp -> ent_emb -> obj_feat)
    ushort* El   = Eh   + 7680000;
    ushort* mW1Th = El    + 7680000;
    ushort* mW1Tl = mW1Th + 1179648;
    ushort* mW2Th = mW1Tl + 1179648;
    ushort* mW2Tl = mW2Th + 589824;
    ushort* WfTh  = mW2Tl + 589824;        // [768][2304] folded
    ushort* WfTl  = WfTh  + 1769472;
    ushort* pW2Th = WfTl  + 1769472;
    ushort* pW2Tl = pW2Th + 589824;
    ushort* W1sTh0 = pW2Tl + 589824;       // 196,608 each x3 steps
    ushort* W1sTl0 = W1sTh0 + 3 * 196608;
    float*  W1s   = (float*)(W1sTl0 + 3 * 196608);
    float*  simb  = W1s  + 196608;
    float*  probs = simb + 20000;
    float*  newe  = probs + 30000;
    float*  h1    = newe + 10000;
    float*  cq    = h1   + 768;
    float*  ctx   = cq   + 768;
    float*  H256  = (float*)HIDh;          // 20000x256 fp32 overlay
    float*  Wfold = (float*)Eh;            // fp32 tmp (dead before E written)

    dim3 B256(256);
    const ushort* np = nullptr;

    // 0) weight prep
    k_fold<<<(2304 * D + 255) / 256, B256, 0, stream>>>(pW1, Wfold, 2304 * D);
    k_wt<<<dim3(48, 24), B256, 0, stream>>>(mW1, mW1Th, mW1Tl, 2 * D, D);
    k_wt<<<dim3(24, 24), B256, 0, stream>>>(mW2, mW2Th, mW2Tl, D, D);
    k_wt<<<dim3(72, 24), B256, 0, stream>>>(Wfold, WfTh, WfTl, 3 * D, D);
    k_wt<<<dim3(24, 24), B256, 0, stream>>>(pW2, pW2Th, pW2Tl, D, D);

    // 1) per-step ctx -> scaled+transposed sim weights
    for (int t = 0; t < NSTEP; ++t) {
        k_vecmat<<<3, 256, 0, stream>>>(q, stW1 + (size_t)t * D * D, stb1 + t * D, h1, D, D, 1);
        k_vecmat<<<3, 256, 0, stream>>>(h1, stW2 + (size_t)t * D * D, stb2 + t * D, cq, D, D, 0);
        k_ctx<<<1, 256, 0, stream>>>(cq, qwh, ctx);
        k_scalew<<<768, 256, 0, stream>>>(ctx, simW1, W1s, D * 256);
        k_wt<<<dim3(24, 8), B256, 0, stream>>>(W1s, W1sTh0 + t * 196608, W1sTl0 + t * 196608,
                                               D, 256);
    }

    // 2) entity mention means -> P1 planes
    k_entmean<<<NENT, 256, 0, stream>>>(para, mpos, mid, MMENT, P1h, P1l);

    // 3) ent_emb
    gemm_m<0, 1, 1><<<474, B256, 0, stream>>>(P1h, P1l, nullptr, nullptr, 0, 0,
        np, np, np, np, mW1Th, mW1Tl, mb1, nullptr, HIDh, HIDl, NENT, D, 2 * D, 6);
    gemm_m<0, 0, 1><<<474, B256, 0, stream>>>(HIDh, HIDl, nullptr, nullptr, 0, 0,
        np, np, np, np, mW2Th, mW2Tl, mb2, nullptr, Eh, El, NENT, D, D, 6);

    // 4) step 0: sim on entities -> probs[0]
    gemm_m<0, 1, 0><<<158, B256, 0, stream>>>(Eh, El, nullptr, nullptr, 0, 0,
        np, np, np, np, W1sTh0, W1sTl0, simb1, H256, nullptr, nullptr, NENT, 256, D, 2);
    k_rowdot<0><<<NENT / 4, 256, 0, stream>>>(H256, simW2, simb2, NENT, simb,
                                              nullptr, nullptr, nullptr);
    k_softmax<<<1, 256, 0, stream>>>(simb, probs, NENT);

    // 5) pair pipeline, chunked; folded pair W1 (K=2304)
    for (int c = 0; c < NPAIR / CHUNK; ++c) {
        const int* pp = ppos + (size_t)c * CHUNK * 5;
        ushort* sdh = P1h + (size_t)c * CHUNK * D;
        ushort* sdl = P1l + (size_t)c * CHUNK * D;
        gemm_m<1, 1, 1><<<474, B256, 0, stream>>>(np, np, para, pp, 1, 2,
            np, np, np, np, mW1Th, mW1Tl, mb1, nullptr, HIDh, HIDl, CHUNK, D, 2 * D, 6);
        gemm_m<0, 0, 1><<<474, B256, 0, stream>>>(HIDh, HIDl, nullptr, nullptr, 0, 0,
            np, np, np, np, mW2Th, mW2Tl, mb2, nullptr, sdh, sdl, CHUNK, D, D, 6);
        gemm_m<1, 1, 1><<<474, B256, 0, stream>>>(np, np, para, pp, 3, 4,
            np, np, np, np, mW1Th, mW1Tl, mb1, nullptr, HIDh, HIDl, CHUNK, D, 2 * D, 6);
        gemm_m<0, 0, 1><<<474, B256, 0, stream>>>(HIDh, HIDl, nullptr, nullptr, 0, 0,
            np, np, np, np, mW2Th, mW2Tl, mb2, nullptr, Eh, El, CHUNK, D, D, 6);
        gemm_m<2, 1, 1><<<474, B256, 0, stream>>>(np, np, nullptr, nullptr, 0, 0,
            sdh, sdl, Eh, El, WfTh, WfTl, pb1, nullptr, HIDh, HIDl, CHUNK, D, 3 * D, 6);
        gemm_m<0, 0, 1><<<474, B256, 0, stream>>>(HIDh, HIDl, nullptr, nullptr, 0, 0,
            np, np, np, np, pW2Th, pW2Tl, pb2, nullptr, sdh, sdl, CHUNK, D, D, 6);
    }

    // 6) steps 1,2: sim on pairs + scatter-propagate
    for (int t = 1; t < NSTEP; ++t) {
        gemm_m<0, 1, 0><<<314, B256, 0, stream>>>(P1h, P1l, nullptr, nullptr, 0, 0,
            np, np, np, np, W1sTh0 + t * 196608, W1sTl0 + t * 196608, simb1,
            H256, nullptr, nullptr, NPAIR, 256, D, 2);
        k_zero<<<40, 256, 0, stream>>>(newe, NENT);
        k_rowdot<1><<<NPAIR / 4, 256, 0, stream>>>(H256, simW2, simb2, NPAIR, nullptr,
                                                   probs + (t - 1) * NENT, pso, newe);
        k_clampstore<<<40, 256, 0, stream>>>(newe, probs + t * NENT, NENT);
    }

    // 7) hop attention + final mix
    k_vecmat<<<1, 256, 0, stream>>>(q, hW1, hb1, h1, D, 256, 1);
    k_vecmat<<<1, 256, 0, stream>>>(h1, hW2, hb2, cq, 256, 3, 0);
    k_final<<<40, 256, 0, stream>>>(probs, cq, (float*)d_out, NENT);
}

// Round 9
// 2999.062 us; speedup vs baseline: 1.4898x; 1.4898x over previous
//
#include <hip/hip_runtime.h>
#include <math.h>

// ---------------------------------------------------------------------------
#define D 768
#define NPARA 32
#define LPARA 512
#define LQ 32
#define NENT 10000
#define MMENT 30000
#define NPAIR 20000
#define NSTEP 3
#define CHUNK 10000

using bf16x8 = __attribute__((ext_vector_type(8))) short;
using f32x4  = __attribute__((ext_vector_type(4))) float;

__device__ __forceinline__ float geluf(float x) {
    return 0.5f * x * (1.0f + erff(x * 0.70710678118654752f));
}
__device__ __forceinline__ float bf2f(ushort h) {
    union { unsigned u; float f; } v; v.u = ((unsigned)h) << 16; return v.f;
}
__device__ __forceinline__ ushort bfhi(float x) {
    union { float f; unsigned u; } v; v.f = x; return (ushort)(v.u >> 16);
}
__device__ __forceinline__ void bfsplit(float x, ushort& h, ushort& l) {
    h = bfhi(x);
    l = bfhi(x - bf2f(h));
}

// ---------------------------------------------------------------------------
// Split-bf16 MFMA GEMM. 64x128 tile (grid-limited occupancy fix), A+B in LDS
// (XOR-swizzled), register prefetch of next A AND B tiles for all modes.
// MODE 0: A = hi/lo bf16 planes [M][K]
// MODE 1: A row r = concat(para[p,t1,:], para[p,t2,:]) fp32 gather, K=1536
// MODE 2: A row r, sections {S, O, S*O} from feat planes, K=2304 (folded W1)
// B: pre-transposed weight planes WT[N][K]. OUTP 0: fp32 C; 1: hi/lo planes.
// ---------------------------------------------------------------------------
#define BM 64
#define BN 128

__device__ __forceinline__ int ldso(int row, int kb) {   // ushort index
    return row * 64 + (((kb) ^ ((row & 7) << 4)) >> 1);
}

template <int MODE, int ACT, int OUTP>
__global__ __launch_bounds__(256, 3) void gemm_m(
    const ushort* __restrict__ Ah, const ushort* __restrict__ Al,
    const float* __restrict__ para, const int* __restrict__ ppos, int c1, int c2,
    const ushort* __restrict__ Sh, const ushort* __restrict__ Sl,
    const ushort* __restrict__ Oh, const ushort* __restrict__ Ol,
    const ushort* __restrict__ Bh, const ushort* __restrict__ Bl,
    const float* __restrict__ bias,
    float* __restrict__ Cf, ushort* __restrict__ Ch, ushort* __restrict__ Cl,
    int M, int N, int K, int nby)
{
    __shared__ ushort sAh[BM * 64], sAl[BM * 64];   // 16 KB
    __shared__ ushort sBh[BN * 64], sBl[BN * 64];   // 32 KB

    // band-major bijective XCD swizzle (m204), col-fastest within a band
    const int nwg = gridDim.x;
    const int q = nwg >> 3, r = nwg & 7;
    const int xcd = blockIdx.x & 7, idx = blockIdx.x >> 3;
    const int wgid = (xcd < r) ? xcd * (q + 1) + idx
                               : r * (q + 1) + (xcd - r) * q + idx;
    const int m0 = (wgid / nby) * BM;
    const int n0 = (wgid % nby) * BN;

    const int tid = threadIdx.x;
    const int lane = tid & 63;
    const int wv = tid >> 6;
    const int wr = (wv >> 1) * 32;   // wave row offset (2 m-frags)
    const int wc = (wv & 1) * 64;    // wave col offset (4 n-frags)
    const int ln = lane & 15;
    const int kg = lane >> 4;

    f32x4 acc[2][4];
#pragma unroll
    for (int i = 0; i < 2; ++i)
#pragma unroll
        for (int j = 0; j < 4; ++j)
#pragma unroll
            for (int e = 0; e < 4; ++e) acc[i][j][e] = 0.0f;

    // A staging: 4 threads/row, 16 k each. B staging: 2 threads/row, 32 k each.
    const int arow = tid >> 2, aq = tid & 3;
    const int brow = tid >> 1, bq = tid & 1;
    const int gm = m0 + arow;
    const bool ok = gm < M;

    int baseL = 0, baseR = 0;
    if (MODE == 1 && ok) {
        int p = ppos[gm * 5];
        baseL = (p * LPARA + ppos[gm * 5 + c1]) * D;
        baseR = (p * LPARA + ppos[gm * 5 + c2]) * D;
    }

    bf16x8 pa[4];     // MODE 0: [0,1]=hi, [2,3]=lo
    float4 pf[4];     // MODE 1: 16 fp32
    ushort4 ps[16];   // MODE 2: S/O hi-lo quads
    bf16x8 pb[8];     // B: [0..3]=hi, [4..7]=lo

    auto prefA = [&](int kt) {
        if (MODE == 0) {
            if (ok) {
                const ushort* gh = Ah + (size_t)gm * K + kt + aq * 16;
                const ushort* gl = Al + (size_t)gm * K + kt + aq * 16;
                pa[0] = *(const bf16x8*)gh; pa[1] = *(const bf16x8*)(gh + 8);
                pa[2] = *(const bf16x8*)gl; pa[3] = *(const bf16x8*)(gl + 8);
            } else {
#pragma unroll
                for (int i = 0; i < 4; ++i)
#pragma unroll
                    for (int z = 0; z < 8; ++z) pa[i][z] = 0;
            }
        } else if (MODE == 1) {
            const int kb = kt + aq * 16;             // never crosses D boundary
            const int gb = (kb < D) ? (baseL + kb) : (baseR + kb - D);
#pragma unroll
            for (int j = 0; j < 4; ++j)
                pf[j] = ok ? *(const float4*)(para + gb + j * 4)
                           : make_float4(0.f, 0.f, 0.f, 0.f);
        } else {
            const int sec = kt / D;
            const size_t rb = (size_t)gm * D + (kt - sec * D) + aq * 16;
            if (ok) {
                if (sec == 0) {
#pragma unroll
                    for (int j = 0; j < 4; ++j) {
                        ps[j]     = *(const ushort4*)(Sh + rb + j * 4);
                        ps[4 + j] = *(const ushort4*)(Sl + rb + j * 4);
                    }
                } else if (sec == 1) {
#pragma unroll
                    for (int j = 0; j < 4; ++j) {
                        ps[j]     = *(const ushort4*)(Oh + rb + j * 4);
                        ps[4 + j] = *(const ushort4*)(Ol + rb + j * 4);
                    }
                } else {
#pragma unroll
                    for (int j = 0; j < 4; ++j) {
                        ps[j]      = *(const ushort4*)(Sh + rb + j * 4);
                        ps[4 + j]  = *(const ushort4*)(Sl + rb + j * 4);
                        ps[8 + j]  = *(const ushort4*)(Oh + rb + j * 4);
                        ps[12 + j] = *(const ushort4*)(Ol + rb + j * 4);
                    }
                }
            }
        }
    };

    auto prefB = [&](int kt) {
        const ushort* gh = Bh + (size_t)(n0 + brow) * K + kt + bq * 32;
        const ushort* gl = Bl + (size_t)(n0 + brow) * K + kt + bq * 32;
#pragma unroll
        for (int i = 0; i < 4; ++i) {
            pb[i]     = *(const bf16x8*)(gh + i * 8);
            pb[4 + i] = *(const bf16x8*)(gl + i * 8);
        }
    };

    auto storeAB = [&](int kt) {
        if (MODE == 0) {
            int o0 = ldso(arow, aq * 32), o1 = ldso(arow, aq * 32 + 16);
            *(bf16x8*)&sAh[o0] = pa[0]; *(bf16x8*)&sAh[o1] = pa[1];
            *(bf16x8*)&sAl[o0] = pa[2]; *(bf16x8*)&sAl[o1] = pa[3];
        } else if (MODE == 1) {
#pragma unroll
            for (int j = 0; j < 4; ++j) {
                ushort4 h, l;
                bfsplit(pf[j].x, h.x, l.x); bfsplit(pf[j].y, h.y, l.y);
                bfsplit(pf[j].z, h.z, l.z); bfsplit(pf[j].w, h.w, l.w);
                int o = ldso(arow, aq * 32 + j * 8);
                *(ushort4*)&sAh[o] = h;
                *(ushort4*)&sAl[o] = l;
            }
        } else {
            const int sec = kt / D;
#pragma unroll
            for (int j = 0; j < 4; ++j) {
                ushort4 h, l;
                if (ok) {
                    float val[4];
                    if (sec < 2) {
#pragma unroll
                        for (int e = 0; e < 4; ++e)
                            val[e] = bf2f((&ps[j].x)[e]) + bf2f((&ps[4 + j].x)[e]);
                    } else {
#pragma unroll
                        for (int e = 0; e < 4; ++e) {
                            float sv = bf2f((&ps[j].x)[e]) + bf2f((&ps[4 + j].x)[e]);
                            float ov = bf2f((&ps[8 + j].x)[e]) + bf2f((&ps[12 + j].x)[e]);
                            val[e] = sv * ov;
                        }
                    }
                    bfsplit(val[0], h.x, l.x); bfsplit(val[1], h.y, l.y);
                    bfsplit(val[2], h.z, l.z); bfsplit(val[3], h.w, l.w);
                } else {
                    h.x = h.y = h.z = h.w = 0; l = h;
                }
                int o = ldso(arow, aq * 32 + j * 8);
                *(ushort4*)&sAh[o] = h;
                *(ushort4*)&sAl[o] = l;
            }
        }
        // B
#pragma unroll
        for (int i = 0; i < 4; ++i) {
            int o = ldso(brow, bq * 64 + i * 16);
            *(bf16x8*)&sBh[o] = pb[i];
            *(bf16x8*)&sBl[o] = pb[4 + i];
        }
    };

    // ---- prologue: prefetch tile 0 ----
    prefA(0);
    prefB(0);

    for (int kt = 0; kt < K; kt += 64) {
        if (kt > 0) __syncthreads();       // all waves done reading old tile
        storeAB(kt);
        __syncthreads();

        const int ktn = kt + 64;
        if (ktn < K) { prefA(ktn); prefB(ktn); }   // hide latency under MFMA

#pragma unroll
        for (int ks = 0; ks < 2; ++ks) {
            bf16x8 fbh[4], fbl[4];
#pragma unroll
            for (int ni = 0; ni < 4; ++ni) {
                int o = ldso(wc + ni * 16 + ln, ks * 64 + kg * 16);
                fbh[ni] = *(const bf16x8*)&sBh[o];
                fbl[ni] = *(const bf16x8*)&sBl[o];
            }
#pragma unroll
            for (int mi = 0; mi < 2; ++mi) {
                int o = ldso(wr + mi * 16 + ln, ks * 64 + kg * 16);
                bf16x8 fah = *(const bf16x8*)&sAh[o];
                bf16x8 fal = *(const bf16x8*)&sAl[o];
#pragma unroll
                for (int ni = 0; ni < 4; ++ni) {
                    acc[mi][ni] = __builtin_amdgcn_mfma_f32_16x16x32_bf16(
                        fah, fbh[ni], acc[mi][ni], 0, 0, 0);
                    acc[mi][ni] = __builtin_amdgcn_mfma_f32_16x16x32_bf16(
                        fah, fbl[ni], acc[mi][ni], 0, 0, 0);
                    acc[mi][ni] = __builtin_amdgcn_mfma_f32_16x16x32_bf16(
                        fal, fbh[ni], acc[mi][ni], 0, 0, 0);
                }
            }
        }
    }

    // ---- epilogue: row = (lane>>4)*4+reg, col = lane&15 ----
#pragma unroll
    for (int mi = 0; mi < 2; ++mi)
#pragma unroll
        for (int ni = 0; ni < 4; ++ni) {
            int col = n0 + wc + ni * 16 + ln;
            f32x4 a = acc[mi][ni];
#pragma unroll
            for (int j = 0; j < 4; ++j) {
                int row = m0 + wr + mi * 16 + kg * 4 + j;
                if (row < M) {
                    float v = a[j] + bias[col];
                    if (ACT == 1) v = geluf(v);
                    if (OUTP == 0) {
                        Cf[(size_t)row * N + col] = v;
                    } else {
                        ushort h, l;
                        bfsplit(v, h, l);
                        Ch[(size_t)row * N + col] = h;
                        Cl[(size_t)row * N + col] = l;
                    }
                }
            }
        }
}

// ---------------------------------------------------------------------------
__global__ __launch_bounds__(256) void k_wt(const float* __restrict__ W,
                                            ushort* __restrict__ WTh,
                                            ushort* __restrict__ WTl, int K, int N)
{
    __shared__ float t[32][33];
    const int k0 = blockIdx.x * 32, n0 = blockIdx.y * 32;
    const int c = threadIdx.x & 31, r8 = threadIdx.x >> 5;
#pragma unroll
    for (int i = 0; i < 4; ++i) {
        int r = r8 + i * 8;
        t[r][c] = W[(size_t)(k0 + r) * N + n0 + c];
    }
    __syncthreads();
#pragma unroll
    for (int i = 0; i < 4; ++i) {
        int r = r8 + i * 8;
        float v = t[c][r];
        ushort h, l;
        bfsplit(v, h, l);
        WTh[(size_t)(n0 + r) * K + k0 + c] = h;
        WTl[(size_t)(n0 + r) * K + k0 + c] = l;
    }
}

// folded pair W1: Wf[2304][768] from pW1[3072][768]
__global__ void k_fold(const float* __restrict__ pW1, float* __restrict__ Wf, int n)
{
    int i = blockIdx.x * blockDim.x + threadIdx.x;
    if (i >= n) return;
    int row = i / D;
    float v;
    if (row < D)            v = pW1[i] - pW1[i + 1536 * D];
    else if (row < 2 * D)   v = pW1[i] + pW1[i + 768 * D];
    else                    v = pW1[i + 768 * D];
    Wf[i] = v;
}

__global__ __launch_bounds__(256) void k_entmean(
    const float* __restrict__ para, const int* __restrict__ mpos,
    const int* __restrict__ mid, int M, ushort* __restrict__ oh, ushort* __restrict__ ol)
{
    __shared__ int sb[2];
    const int e = blockIdx.x;
    if (threadIdx.x < 2) {
        int target = e + threadIdx.x;
        int lo = 0, hi = M;
        while (lo < hi) {
            int md = (lo + hi) >> 1;
            if (mid[md] < target) lo = md + 1; else hi = md;
        }
        sb[threadIdx.x] = lo;
    }
    __syncthreads();
    const int lo = sb[0], hi = sb[1];
    const int tid = threadIdx.x;
    float a0 = 0, a1 = 0, a2 = 0, b0 = 0, b1 = 0, b2 = 0;
    for (int m = lo; m < hi; ++m) {
        int p = mpos[m * 3], t1 = mpos[m * 3 + 1], t2 = mpos[m * 3 + 2];
        const float* L = para + (size_t)(p * LPARA + t1) * D;
        const float* R = para + (size_t)(p * LPARA + t2) * D;
        a0 += L[tid]; a1 += L[tid + 256]; a2 += L[tid + 512];
        b0 += R[tid]; b1 += R[tid + 256]; b2 += R[tid + 512];
    }
    const float inv = (hi > lo) ? 1.0f / (float)(hi - lo) : 0.0f;
    size_t base = (size_t)e * (2 * D);
    float vals[6] = { a0 * inv, a1 * inv, a2 * inv, b0 * inv, b1 * inv, b2 * inv };
    int offs[6] = { tid, tid + 256, tid + 512, D + tid, D + tid + 256, D + tid + 512 };
#pragma unroll
    for (int i = 0; i < 6; ++i) {
        ushort h, l;
        bfsplit(vals[i], h, l);
        oh[base + offs[i]] = h;
        ol[base + offs[i]] = l;
    }
}

__global__ void k_vecmat(const float* __restrict__ x, const float* __restrict__ W,
                         const float* __restrict__ b, float* __restrict__ out,
                         int K, int N, int act)
{
    int j = blockIdx.x * blockDim.x + threadIdx.x;
    if (j >= N) return;
    float s = 0.0f;
    for (int k = 0; k < K; ++k) s = fmaf(x[k], W[(size_t)k * N + j], s);
    s += b[j];
    if (act) s = geluf(s);
    out[j] = s;
}

__global__ void k_ctx(const float* __restrict__ cq, const float* __restrict__ qwh,
                      float* __restrict__ ctx)
{
    __shared__ float red[256];
    __shared__ float dist[LQ];
    const int tid = threadIdx.x;
    const int l = tid >> 3, part = tid & 7;
    float s = 0.0f;
    for (int d = part; d < D; d += 8) s += cq[d] * qwh[l * D + d];
    red[tid] = s;
    __syncthreads();
    if (part == 0) {
        float v = 0;
        for (int i = 0; i < 8; ++i) v += red[l * 8 + i];
        dist[l] = v;
    }
    __syncthreads();
    if (tid == 0) {
        float mx = -1e30f;
        for (int i = 0; i < LQ; ++i) mx = fmaxf(mx, dist[i]);
        float sm = 0;
        for (int i = 0; i < LQ; ++i) { float e = expf(dist[i] - mx); dist[i] = e; sm += e; }
        float inv = 1.0f / sm;
        for (int i = 0; i < LQ; ++i) dist[i] *= inv;
    }
    __syncthreads();
    for (int d = tid; d < D; d += 256) {
        float v = 0;
#pragma unroll
        for (int l2 = 0; l2 < LQ; ++l2) v += dist[l2] * qwh[l2 * D + d];
        ctx[d] = v + cq[d];
    }
}

__global__ void k_scalew(const float* __restrict__ ctx, const float* __restrict__ w1,
                         float* __restrict__ o, int n)
{
    int i = blockIdx.x * 256 + threadIdx.x;
    if (i < n) o[i] = ctx[i >> 8] * w1[i];
}

template <int PAIRMODE>
__global__ void k_rowdot(const float* __restrict__ H, const float* __restrict__ w2,
                         const float* __restrict__ sb2, int Nr,
                         float* __restrict__ simout,
                         const float* __restrict__ laste, const int* __restrict__ so,
                         float* __restrict__ newe)
{
    int r = blockIdx.x * 4 + (threadIdx.x >> 6);
    int lane = threadIdx.x & 63;
    if (r >= Nr) return;
    float s = 0.0f;
#pragma unroll
    for (int i = 0; i < 4; ++i)
        s += H[(size_t)r * 256 + lane + i * 64] * w2[lane + i * 64];
    for (int off = 32; off > 0; off >>= 1) s += __shfl_down(s, off, 64);
    if (lane == 0) {
        s += sb2[0];
        if (PAIRMODE == 0) {
            simout[r] = s;
        } else {
            float p = 1.0f / (1.0f + expf(-s));
            float v = laste[so[r * 2]] * p;
            atomicAdd(&newe[so[r * 2 + 1]], v);
        }
    }
}

__global__ void k_softmax(const float* __restrict__ sim, float* __restrict__ outp, int n)
{
    __shared__ float red[256];
    __shared__ float s_mx, s_sum;
    const int tid = threadIdx.x;
    float mx = -1e30f;
    for (int i = tid; i < n; i += 256) mx = fmaxf(mx, sim[i]);
    red[tid] = mx; __syncthreads();
    for (int off = 128; off > 0; off >>= 1) {
        if (tid < off) red[tid] = fmaxf(red[tid], red[tid + off]);
        __syncthreads();
    }
    if (tid == 0) s_mx = red[0];
    __syncthreads();
    const float mxv = s_mx;
    float sum = 0;
    for (int i = tid; i < n; i += 256) sum += expf(sim[i] - mxv);
    red[tid] = sum; __syncthreads();
    for (int off = 128; off > 0; off >>= 1) {
        if (tid < off) red[tid] += red[tid + off];
        __syncthreads();
    }
    if (tid == 0) s_sum = red[0];
    __syncthreads();
    const float inv = 1.0f / s_sum;
    for (int i = tid; i < n; i += 256) {
        float v = expf(sim[i] - mxv) * inv;
        outp[i] = v / fmaxf(v, 1.0f);
    }
}

__global__ void k_zero(float* p, int n)
{
    int i = blockIdx.x * blockDim.x + threadIdx.x;
    if (i < n) p[i] = 0.0f;
}

__global__ void k_clampstore(const float* __restrict__ ne, float* __restrict__ outp, int n)
{
    int i = blockIdx.x * blockDim.x + threadIdx.x;
    if (i < n) { float v = ne[i]; outp[i] = v / fmaxf(v, 1.0f); }
}

__global__ void k_final(const float* __restrict__ probs, const float* __restrict__ hlog,
                        float* __restrict__ out, int n)
{
    int i = blockIdx.x * blockDim.x + threadIdx.x;
    if (i >= n) return;
    float l0 = hlog[0], l1 = hlog[1], l2 = hlog[2];
    float m = fmaxf(l0, fmaxf(l1, l2));
    float e0 = expf(l0 - m), e1 = expf(l1 - m), e2 = expf(l2 - m);
    float inv = 1.0f / (e0 + e1 + e2);
    out[i] = (e0 * probs[i] + e1 * probs[n + i] + e2 * probs[2 * n + i]) * inv;
}

// ---------------------------------------------------------------------------
extern "C" void kernel_launch(void* const* d_in, const int* in_sizes, int n_in,
                              void* d_out, int out_size, void* d_ws, size_t ws_size,
                              hipStream_t stream)
{
    const size_t WS_NEED = 142790016;  // 136.2 MiB
    if (ws_size < WS_NEED) return;

    const float* para  = (const float*)d_in[0];
    const float* q     = (const float*)d_in[1];
    const float* qwh   = (const float*)d_in[2];
    const float* stW1  = (const float*)d_in[3];
    const float* stb1  = (const float*)d_in[4];
    const float* stW2  = (const float*)d_in[5];
    const float* stb2  = (const float*)d_in[6];
    const float* mW1   = (const float*)d_in[7];
    const float* mb1   = (const float*)d_in[8];
    const float* mW2   = (const float*)d_in[9];
    const float* mb2   = (const float*)d_in[10];
    const float* pW1   = (const float*)d_in[11];
    const float* pb1   = (const float*)d_in[12];
    const float* pW2   = (const float*)d_in[13];
    const float* pb2   = (const float*)d_in[14];
    const float* simW1 = (const float*)d_in[15];
    const float* simb1 = (const float*)d_in[16];
    const float* simW2 = (const float*)d_in[17];
    const float* simb2 = (const float*)d_in[18];
    const float* hW1   = (const float*)d_in[19];
    const float* hb1   = (const float*)d_in[20];
    const float* hW2   = (const float*)d_in[21];
    const float* hb2   = (const float*)d_in[22];
    const int*   mpos  = (const int*)d_in[23];
    const int*   mid   = (const int*)d_in[24];
    const int*   ppos  = (const int*)d_in[25];
    const int*   pso   = (const int*)d_in[26];

    // ---- workspace layout ----
    ushort* P1h  = (ushort*)d_ws;          // 15,360,000 (EM -> sub_feat -> pair_emb)
    ushort* P1l  = P1h  + 15360000;
    ushort* HIDh = P1l  + 15360000;        //  7,680,000 (hidden; H256 fp32 overlay)
    ushort* HIDl = HIDh + 7680000;
    ushort* Eh   = HIDl + 7680000;         //  7,680,000 (Wfold tmp -> ent_emb -> obj_feat)
    ushort* El   = Eh   + 7680000;
    ushort* mW1Th = El    + 7680000;
    ushort* mW1Tl = mW1Th + 1179648;
    ushort* mW2Th = mW1Tl + 1179648;
    ushort* mW2Tl = mW2Th + 589824;
    ushort* WfTh  = mW2Tl + 589824;        // [768][2304] folded
    ushort* WfTl  = WfTh  + 1769472;
    ushort* pW2Th = WfTl  + 1769472;
    ushort* pW2Tl = pW2Th + 589824;
    ushort* W1sTh0 = pW2Tl + 589824;       // 196,608 each x3 steps
    ushort* W1sTl0 = W1sTh0 + 3 * 196608;
    float*  W1s   = (float*)(W1sTl0 + 3 * 196608);
    float*  simb  = W1s  + 196608;
    float*  probs = simb + 20000;
    float*  newe  = probs + 30000;
    float*  h1    = newe + 10000;
    float*  cq    = h1   + 768;
    float*  ctx   = cq   + 768;
    float*  H256  = (float*)HIDh;          // 20000x256 fp32 overlay
    float*  Wfold = (float*)Eh;            // fp32 tmp (dead before E written)

    dim3 B256(256);
    const ushort* np = nullptr;

    // 0) weight prep
    k_fold<<<(2304 * D + 255) / 256, B256, 0, stream>>>(pW1, Wfold, 2304 * D);
    k_wt<<<dim3(48, 24), B256, 0, stream>>>(mW1, mW1Th, mW1Tl, 2 * D, D);
    k_wt<<<dim3(24, 24), B256, 0, stream>>>(mW2, mW2Th, mW2Tl, D, D);
    k_wt<<<dim3(72, 24), B256, 0, stream>>>(Wfold, WfTh, WfTl, 3 * D, D);
    k_wt<<<dim3(24, 24), B256, 0, stream>>>(pW2, pW2Th, pW2Tl, D, D);

    // 1) per-step ctx -> scaled+transposed sim weights
    for (int t = 0; t < NSTEP; ++t) {
        k_vecmat<<<3, 256, 0, stream>>>(q, stW1 + (size_t)t * D * D, stb1 + t * D, h1, D, D, 1);
        k_vecmat<<<3, 256, 0, stream>>>(h1, stW2 + (size_t)t * D * D, stb2 + t * D, cq, D, D, 0);
        k_ctx<<<1, 256, 0, stream>>>(cq, qwh, ctx);
        k_scalew<<<768, 256, 0, stream>>>(ctx, simW1, W1s, D * 256);
        k_wt<<<dim3(24, 8), B256, 0, stream>>>(W1s, W1sTh0 + t * 196608, W1sTl0 + t * 196608,
                                               D, 256);
    }

    // 2) entity mention means -> P1 planes
    k_entmean<<<NENT, 256, 0, stream>>>(para, mpos, mid, MMENT, P1h, P1l);

    // 3) ent_emb  (grids: ceil(10000/64)=157 m-tiles x nby)
    gemm_m<0, 1, 1><<<942, B256, 0, stream>>>(P1h, P1l, nullptr, nullptr, 0, 0,
        np, np, np, np, mW1Th, mW1Tl, mb1, nullptr, HIDh, HIDl, NENT, D, 2 * D, 6);
    gemm_m<0, 0, 1><<<942, B256, 0, stream>>>(HIDh, HIDl, nullptr, nullptr, 0, 0,
        np, np, np, np, mW2Th, mW2Tl, mb2, nullptr, Eh, El, NENT, D, D, 6);

    // 4) step 0: sim on entities -> probs[0]
    gemm_m<0, 1, 0><<<314, B256, 0, stream>>>(Eh, El, nullptr, nullptr, 0, 0,
        np, np, np, np, W1sTh0, W1sTl0, simb1, H256, nullptr, nullptr, NENT, 256, D, 2);
    k_rowdot<0><<<NENT / 4, 256, 0, stream>>>(H256, simW2, simb2, NENT, simb,
                                              nullptr, nullptr, nullptr);
    k_softmax<<<1, 256, 0, stream>>>(simb, probs, NENT);

    // 5) pair pipeline, chunked; folded pair W1 (K=2304)
    for (int c = 0; c < NPAIR / CHUNK; ++c) {
        const int* pp = ppos + (size_t)c * CHUNK * 5;
        ushort* sdh = P1h + (size_t)c * CHUNK * D;
        ushort* sdl = P1l + (size_t)c * CHUNK * D;
        gemm_m<1, 1, 1><<<942, B256, 0, stream>>>(np, np, para, pp, 1, 2,
            np, np, np, np, mW1Th, mW1Tl, mb1, nullptr, HIDh, HIDl, CHUNK, D, 2 * D, 6);
        gemm_m<0, 0, 1><<<942, B256, 0, stream>>>(HIDh, HIDl, nullptr, nullptr, 0, 0,
            np, np, np, np, mW2Th, mW2Tl, mb2, nullptr, sdh, sdl, CHUNK, D, D, 6);
        gemm_m<1, 1, 1><<<942, B256, 0, stream>>>(np, np, para, pp, 3, 4,
            np, np, np, np, mW1Th, mW1Tl, mb1, nullptr, HIDh, HIDl, CHUNK, D, 2 * D, 6);
        gemm_m<0, 0, 1><<<942, B256, 0, stream>>>(HIDh, HIDl, nullptr, nullptr, 0, 0,
            np, np, np, np, mW2Th, mW2Tl, mb2, nullptr, Eh, El, CHUNK, D, D, 6);
        gemm_m<2, 1, 1><<<942, B256, 0, stream>>>(np, np, nullptr, nullptr, 0, 0,
            sdh, sdl, Eh, El, WfTh, WfTl, pb1, nullptr, HIDh, HIDl, CHUNK, D, 3 * D, 6);
        gemm_m<0, 0, 1><<<942, B256, 0, stream>>>(HIDh, HIDl, nullptr, nullptr, 0, 0,
            np, np, np, np, pW2Th, pW2Tl, pb2, nullptr, sdh, sdl, CHUNK, D, D, 6);
    }

    // 6) steps 1,2: sim on pairs + scatter-propagate
    for (int t = 1; t < NSTEP; ++t) {
        gemm_m<0, 1, 0><<<626, B256, 0, stream>>>(P1h, P1l, nullptr, nullptr, 0, 0,
            np, np, np, np, W1sTh0 + t * 196608, W1sTl0 + t * 196608, simb1,
            H256, nullptr, nullptr, NPAIR, 256, D, 2);
        k_zero<<<40, 256, 0, stream>>>(newe, NENT);
        k_rowdot<1><<<NPAIR / 4, 256, 0, stream>>>(H256, simW2, simb2, NPAIR, nullptr,
                                                   probs + (t - 1) * NENT, pso, newe);
        k_clampstore<<<40, 256, 0, stream>>>(newe, probs + t * NENT, NENT);
    }

    // 7) hop attention + final mix
    k_vecmat<<<1, 256, 0, stream>>>(q, hW1, hb1, h1, D, 256, 1);
    k_vecmat<<<1, 256, 0, stream>>>(h1, hW2, hb2, cq, 256, 3, 0);
    k_final<<<40, 256, 0, stream>>>(probs, cq, (float*)d_out, NENT);
}

// Round 10
// 1597.744 us; speedup vs baseline: 2.7964x; 1.8771x over previous
//
#include <hip/hip_runtime.h>
#include <math.h>

// ---------------------------------------------------------------------------
#define D 768
#define NPARA 32
#define LPARA 512
#define LQ 32
#define NENT 10000
#define MMENT 30000
#define NPAIR 20000
#define NSTEP 3
#define CHUNK 10000

using bf16x8 = __attribute__((ext_vector_type(8))) short;
using f32x4  = __attribute__((ext_vector_type(4))) float;

__device__ __forceinline__ float geluf(float x) {
    return 0.5f * x * (1.0f + erff(x * 0.70710678118654752f));
}
__device__ __forceinline__ float bf2f(ushort h) {
    union { unsigned u; float f; } v; v.u = ((unsigned)h) << 16; return v.f;
}
__device__ __forceinline__ ushort bfhi(float x) {
    union { float f; unsigned u; } v; v.f = x; return (ushort)(v.u >> 16);
}
__device__ __forceinline__ void bfsplit(float x, ushort& h, ushort& l) {
    h = bfhi(x);
    l = bfhi(x - bf2f(h));
}

// ---------------------------------------------------------------------------
// Split-bf16 MFMA GEMM. 64x128 tile, A+B LDS (XOR-swizzled), register
// prefetch of next A and B tiles, band-major XCD swizzle. (unchanged, R9)
// ---------------------------------------------------------------------------
#define BM 64
#define BN 128

__device__ __forceinline__ int ldso(int row, int kb) {   // ushort index
    return row * 64 + (((kb) ^ ((row & 7) << 4)) >> 1);
}

template <int MODE, int ACT, int OUTP>
__global__ __launch_bounds__(256, 3) void gemm_m(
    const ushort* __restrict__ Ah, const ushort* __restrict__ Al,
    const float* __restrict__ para, const int* __restrict__ ppos, int c1, int c2,
    const ushort* __restrict__ Sh, const ushort* __restrict__ Sl,
    const ushort* __restrict__ Oh, const ushort* __restrict__ Ol,
    const ushort* __restrict__ Bh, const ushort* __restrict__ Bl,
    const float* __restrict__ bias,
    float* __restrict__ Cf, ushort* __restrict__ Ch, ushort* __restrict__ Cl,
    int M, int N, int K, int nby)
{
    __shared__ ushort sAh[BM * 64], sAl[BM * 64];
    __shared__ ushort sBh[BN * 64], sBl[BN * 64];

    const int nwg = gridDim.x;
    const int q = nwg >> 3, r = nwg & 7;
    const int xcd = blockIdx.x & 7, idx = blockIdx.x >> 3;
    const int wgid = (xcd < r) ? xcd * (q + 1) + idx
                               : r * (q + 1) + (xcd - r) * q + idx;
    const int m0 = (wgid / nby) * BM;
    const int n0 = (wgid % nby) * BN;

    const int tid = threadIdx.x;
    const int lane = tid & 63;
    const int wv = tid >> 6;
    const int wr = (wv >> 1) * 32;
    const int wc = (wv & 1) * 64;
    const int ln = lane & 15;
    const int kg = lane >> 4;

    f32x4 acc[2][4];
#pragma unroll
    for (int i = 0; i < 2; ++i)
#pragma unroll
        for (int j = 0; j < 4; ++j)
#pragma unroll
            for (int e = 0; e < 4; ++e) acc[i][j][e] = 0.0f;

    const int arow = tid >> 2, aq = tid & 3;
    const int brow = tid >> 1, bq = tid & 1;
    const int gm = m0 + arow;
    const bool ok = gm < M;

    int baseL = 0, baseR = 0;
    if (MODE == 1 && ok) {
        int p = ppos[gm * 5];
        baseL = (p * LPARA + ppos[gm * 5 + c1]) * D;
        baseR = (p * LPARA + ppos[gm * 5 + c2]) * D;
    }

    bf16x8 pa[4];
    float4 pf[4];
    ushort4 ps[16];
    bf16x8 pb[8];

    auto prefA = [&](int kt) {
        if (MODE == 0) {
            if (ok) {
                const ushort* gh = Ah + (size_t)gm * K + kt + aq * 16;
                const ushort* gl = Al + (size_t)gm * K + kt + aq * 16;
                pa[0] = *(const bf16x8*)gh; pa[1] = *(const bf16x8*)(gh + 8);
                pa[2] = *(const bf16x8*)gl; pa[3] = *(const bf16x8*)(gl + 8);
            } else {
#pragma unroll
                for (int i = 0; i < 4; ++i)
#pragma unroll
                    for (int z = 0; z < 8; ++z) pa[i][z] = 0;
            }
        } else if (MODE == 1) {
            const int kb = kt + aq * 16;
            const int gb = (kb < D) ? (baseL + kb) : (baseR + kb - D);
#pragma unroll
            for (int j = 0; j < 4; ++j)
                pf[j] = ok ? *(const float4*)(para + gb + j * 4)
                           : make_float4(0.f, 0.f, 0.f, 0.f);
        } else {
            const int sec = kt / D;
            const size_t rb = (size_t)gm * D + (kt - sec * D) + aq * 16;
            if (ok) {
                if (sec == 0) {
#pragma unroll
                    for (int j = 0; j < 4; ++j) {
                        ps[j]     = *(const ushort4*)(Sh + rb + j * 4);
                        ps[4 + j] = *(const ushort4*)(Sl + rb + j * 4);
                    }
                } else if (sec == 1) {
#pragma unroll
                    for (int j = 0; j < 4; ++j) {
                        ps[j]     = *(const ushort4*)(Oh + rb + j * 4);
                        ps[4 + j] = *(const ushort4*)(Ol + rb + j * 4);
                    }
                } else {
#pragma unroll
                    for (int j = 0; j < 4; ++j) {
                        ps[j]      = *(const ushort4*)(Sh + rb + j * 4);
                        ps[4 + j]  = *(const ushort4*)(Sl + rb + j * 4);
                        ps[8 + j]  = *(const ushort4*)(Oh + rb + j * 4);
                        ps[12 + j] = *(const ushort4*)(Ol + rb + j * 4);
                    }
                }
            }
        }
    };

    auto prefB = [&](int kt) {
        const ushort* gh = Bh + (size_t)(n0 + brow) * K + kt + bq * 32;
        const ushort* gl = Bl + (size_t)(n0 + brow) * K + kt + bq * 32;
#pragma unroll
        for (int i = 0; i < 4; ++i) {
            pb[i]     = *(const bf16x8*)(gh + i * 8);
            pb[4 + i] = *(const bf16x8*)(gl + i * 8);
        }
    };

    auto storeAB = [&](int kt) {
        if (MODE == 0) {
            int o0 = ldso(arow, aq * 32), o1 = ldso(arow, aq * 32 + 16);
            *(bf16x8*)&sAh[o0] = pa[0]; *(bf16x8*)&sAh[o1] = pa[1];
            *(bf16x8*)&sAl[o0] = pa[2]; *(bf16x8*)&sAl[o1] = pa[3];
        } else if (MODE == 1) {
#pragma unroll
            for (int j = 0; j < 4; ++j) {
                ushort4 h, l;
                bfsplit(pf[j].x, h.x, l.x); bfsplit(pf[j].y, h.y, l.y);
                bfsplit(pf[j].z, h.z, l.z); bfsplit(pf[j].w, h.w, l.w);
                int o = ldso(arow, aq * 32 + j * 8);
                *(ushort4*)&sAh[o] = h;
                *(ushort4*)&sAl[o] = l;
            }
        } else {
            const int sec = kt / D;
#pragma unroll
            for (int j = 0; j < 4; ++j) {
                ushort4 h, l;
                if (ok) {
                    float val[4];
                    if (sec < 2) {
#pragma unroll
                        for (int e = 0; e < 4; ++e)
                            val[e] = bf2f((&ps[j].x)[e]) + bf2f((&ps[4 + j].x)[e]);
                    } else {
#pragma unroll
                        for (int e = 0; e < 4; ++e) {
                            float sv = bf2f((&ps[j].x)[e]) + bf2f((&ps[4 + j].x)[e]);
                            float ov = bf2f((&ps[8 + j].x)[e]) + bf2f((&ps[12 + j].x)[e]);
                            val[e] = sv * ov;
                        }
                    }
                    bfsplit(val[0], h.x, l.x); bfsplit(val[1], h.y, l.y);
                    bfsplit(val[2], h.z, l.z); bfsplit(val[3], h.w, l.w);
                } else {
                    h.x = h.y = h.z = h.w = 0; l = h;
                }
                int o = ldso(arow, aq * 32 + j * 8);
                *(ushort4*)&sAh[o] = h;
                *(ushort4*)&sAl[o] = l;
            }
        }
#pragma unroll
        for (int i = 0; i < 4; ++i) {
            int o = ldso(brow, bq * 64 + i * 16);
            *(bf16x8*)&sBh[o] = pb[i];
            *(bf16x8*)&sBl[o] = pb[4 + i];
        }
    };

    prefA(0);
    prefB(0);

    for (int kt = 0; kt < K; kt += 64) {
        if (kt > 0) __syncthreads();
        storeAB(kt);
        __syncthreads();

        const int ktn = kt + 64;
        if (ktn < K) { prefA(ktn); prefB(ktn); }

#pragma unroll
        for (int ks = 0; ks < 2; ++ks) {
            bf16x8 fbh[4], fbl[4];
#pragma unroll
            for (int ni = 0; ni < 4; ++ni) {
                int o = ldso(wc + ni * 16 + ln, ks * 64 + kg * 16);
                fbh[ni] = *(const bf16x8*)&sBh[o];
                fbl[ni] = *(const bf16x8*)&sBl[o];
            }
#pragma unroll
            for (int mi = 0; mi < 2; ++mi) {
                int o = ldso(wr + mi * 16 + ln, ks * 64 + kg * 16);
                bf16x8 fah = *(const bf16x8*)&sAh[o];
                bf16x8 fal = *(const bf16x8*)&sAl[o];
#pragma unroll
                for (int ni = 0; ni < 4; ++ni) {
                    acc[mi][ni] = __builtin_amdgcn_mfma_f32_16x16x32_bf16(
                        fah, fbh[ni], acc[mi][ni], 0, 0, 0);
                    acc[mi][ni] = __builtin_amdgcn_mfma_f32_16x16x32_bf16(
                        fah, fbl[ni], acc[mi][ni], 0, 0, 0);
                    acc[mi][ni] = __builtin_amdgcn_mfma_f32_16x16x32_bf16(
                        fal, fbh[ni], acc[mi][ni], 0, 0, 0);
                }
            }
        }
    }

#pragma unroll
    for (int mi = 0; mi < 2; ++mi)
#pragma unroll
        for (int ni = 0; ni < 4; ++ni) {
            int col = n0 + wc + ni * 16 + ln;
            f32x4 a = acc[mi][ni];
#pragma unroll
            for (int j = 0; j < 4; ++j) {
                int row = m0 + wr + mi * 16 + kg * 4 + j;
                if (row < M) {
                    float v = a[j] + bias[col];
                    if (ACT == 1) v = geluf(v);
                    if (OUTP == 0) {
                        Cf[(size_t)row * N + col] = v;
                    } else {
                        ushort h, l;
                        bfsplit(v, h, l);
                        Ch[(size_t)row * N + col] = h;
                        Cl[(size_t)row * N + col] = l;
                    }
                }
            }
        }
}

// ---------------------------------------------------------------------------
__global__ __launch_bounds__(256) void k_wt(const float* __restrict__ W,
                                            ushort* __restrict__ WTh,
                                            ushort* __restrict__ WTl, int K, int N)
{
    __shared__ float t[32][33];
    const int k0 = blockIdx.x * 32, n0 = blockIdx.y * 32;
    const int c = threadIdx.x & 31, r8 = threadIdx.x >> 5;
#pragma unroll
    for (int i = 0; i < 4; ++i) {
        int r = r8 + i * 8;
        t[r][c] = W[(size_t)(k0 + r) * N + n0 + c];
    }
    __syncthreads();
#pragma unroll
    for (int i = 0; i < 4; ++i) {
        int r = r8 + i * 8;
        float v = t[c][r];
        ushort h, l;
        bfsplit(v, h, l);
        WTh[(size_t)(n0 + r) * K + k0 + c] = h;
        WTl[(size_t)(n0 + r) * K + k0 + c] = l;
    }
}

// folded pair W1: Wf[2304][768] from pW1[3072][768]
__global__ void k_fold(const float* __restrict__ pW1, float* __restrict__ Wf, int n)
{
    int i = blockIdx.x * blockDim.x + threadIdx.x;
    if (i >= n) return;
    int row = i / D;
    float v;
    if (row < D)            v = pW1[i] - pW1[i + 1536 * D];
    else if (row < 2 * D)   v = pW1[i] + pW1[i + 768 * D];
    else                    v = pW1[i + 768 * D];
    Wf[i] = v;
}

__global__ __launch_bounds__(256) void k_entmean(
    const float* __restrict__ para, const int* __restrict__ mpos,
    const int* __restrict__ mid, int M, ushort* __restrict__ oh, ushort* __restrict__ ol)
{
    __shared__ int sb[2];
    const int e = blockIdx.x;
    if (threadIdx.x < 2) {
        int target = e + threadIdx.x;
        int lo = 0, hi = M;
        while (lo < hi) {
            int md = (lo + hi) >> 1;
            if (mid[md] < target) lo = md + 1; else hi = md;
        }
        sb[threadIdx.x] = lo;
    }
    __syncthreads();
    const int lo = sb[0], hi = sb[1];
    const int tid = threadIdx.x;
    float a0 = 0, a1 = 0, a2 = 0, b0 = 0, b1 = 0, b2 = 0;
    for (int m = lo; m < hi; ++m) {
        int p = mpos[m * 3], t1 = mpos[m * 3 + 1], t2 = mpos[m * 3 + 2];
        const float* L = para + (size_t)(p * LPARA + t1) * D;
        const float* R = para + (size_t)(p * LPARA + t2) * D;
        a0 += L[tid]; a1 += L[tid + 256]; a2 += L[tid + 512];
        b0 += R[tid]; b1 += R[tid + 256]; b2 += R[tid + 512];
    }
    const float inv = (hi > lo) ? 1.0f / (float)(hi - lo) : 0.0f;
    size_t base = (size_t)e * (2 * D);
    float vals[6] = { a0 * inv, a1 * inv, a2 * inv, b0 * inv, b1 * inv, b2 * inv };
    int offs[6] = { tid, tid + 256, tid + 512, D + tid, D + tid + 256, D + tid + 512 };
#pragma unroll
    for (int i = 0; i < 6; ++i) {
        ushort h, l;
        bfsplit(vals[i], h, l);
        oh[base + offs[i]] = h;
        ol[base + offs[i]] = l;
    }
}

// ---------------------------------------------------------------------------
// Batched split-K matvec (deterministic, no atomics).
// acc[((t*nks)+ks)*N + j] = sum_{k in slice(ks,kq)} x_t[k] * W_t[k*N+j]
// grid (N/64, nks, T); block 256 = 64 j-cols x 4 k-groups.
// ---------------------------------------------------------------------------
__global__ __launch_bounds__(256) void k_mvpart(
    const float* __restrict__ x, int xstride,
    const float* __restrict__ W, float* __restrict__ acc, int K, int N, int nks)
{
    const int t = blockIdx.z;
    const float* xt = x + (size_t)t * xstride;
    const float* Wt = W + (size_t)t * K * N;
    const int jj = threadIdx.x & 63;
    const int kq = threadIdx.x >> 6;
    const int j = blockIdx.x * 64 + jj;
    const int kchunk = K / (nks * 4);
    const int kbeg = (blockIdx.y * 4 + kq) * kchunk;
    float s = 0.0f;
    for (int k = kbeg; k < kbeg + kchunk; ++k)
        s = fmaf(xt[k], Wt[(size_t)k * N + j], s);
    __shared__ float red[256];
    red[threadIdx.x] = s;
    __syncthreads();
    if (kq == 0) {
        float v = red[jj] + red[64 + jj] + red[128 + jj] + red[192 + jj];
        acc[((size_t)(t * nks) + blockIdx.y) * N + j] = v;
    }
}

// out[t*N+j] = act(sum_s acc[(t*nks+s)*N+j] + b[t*N+j]); grid (N/256, T)
__global__ void k_biasact(const float* __restrict__ acc, const float* __restrict__ b,
                          float* __restrict__ out, int N, int nks, int act)
{
    const int t = blockIdx.y;
    const int j = blockIdx.x * 256 + threadIdx.x;
    if (j >= N) return;
    float s = 0.0f;
    for (int i = 0; i < nks; ++i) s += acc[((size_t)(t * nks) + i) * N + j];
    s += b[(size_t)t * N + j];
    if (act) s = geluf(s);
    out[(size_t)t * N + j] = s;
}

// hlog[j] = x(256) . W[256][3] + b[j]
__global__ void k_dot3(const float* __restrict__ x, const float* __restrict__ W,
                       const float* __restrict__ b, float* __restrict__ out)
{
    int j = threadIdx.x >> 6, lane = threadIdx.x & 63;
    if (j >= 3) return;
    float s = 0.0f;
#pragma unroll
    for (int i = 0; i < 4; ++i) {
        int k = lane + i * 64;
        s += x[k] * W[k * 3 + j];
    }
    for (int off = 32; off > 0; off >>= 1) s += __shfl_down(s, off, 64);
    if (lane == 0) out[j] = s + b[j];
}

// ctx_t = softmax(cq_t . qwh_l) @ qwh + cq_t ; grid (T)
__global__ void k_ctx3(const float* __restrict__ cq3, const float* __restrict__ qwh,
                       float* __restrict__ ctx3)
{
    const float* cq = cq3 + (size_t)blockIdx.x * D;
    float* ctx = ctx3 + (size_t)blockIdx.x * D;
    __shared__ float red[256];
    __shared__ float dist[LQ];
    const int tid = threadIdx.x;
    const int l = tid >> 3, part = tid & 7;
    float s = 0.0f;
    for (int d = part; d < D; d += 8) s += cq[d] * qwh[l * D + d];
    red[tid] = s;
    __syncthreads();
    if (part == 0) {
        float v = 0;
        for (int i = 0; i < 8; ++i) v += red[l * 8 + i];
        dist[l] = v;
    }
    __syncthreads();
    if (tid == 0) {
        float mx = -1e30f;
        for (int i = 0; i < LQ; ++i) mx = fmaxf(mx, dist[i]);
        float sm = 0;
        for (int i = 0; i < LQ; ++i) { float e = expf(dist[i] - mx); dist[i] = e; sm += e; }
        float inv = 1.0f / sm;
        for (int i = 0; i < LQ; ++i) dist[i] *= inv;
    }
    __syncthreads();
    for (int d = tid; d < D; d += 256) {
        float v = 0;
#pragma unroll
        for (int l2 = 0; l2 < LQ; ++l2) v += dist[l2] * qwh[l2 * D + d];
        ctx[d] = v + cq[d];
    }
}

__global__ void k_scalew(const float* __restrict__ ctx, const float* __restrict__ w1,
                         float* __restrict__ o, int n)
{
    int i = blockIdx.x * 256 + threadIdx.x;
    if (i < n) o[i] = ctx[i >> 8] * w1[i];
}

template <int PAIRMODE>
__global__ void k_rowdot(const float* __restrict__ H, const float* __restrict__ w2,
                         const float* __restrict__ sb2, int Nr,
                         float* __restrict__ simout,
                         const float* __restrict__ laste, const int* __restrict__ so,
                         float* __restrict__ newe)
{
    int r = blockIdx.x * 4 + (threadIdx.x >> 6);
    int lane = threadIdx.x & 63;
    if (r >= Nr) return;
    float s = 0.0f;
#pragma unroll
    for (int i = 0; i < 4; ++i)
        s += H[(size_t)r * 256 + lane + i * 64] * w2[lane + i * 64];
    for (int off = 32; off > 0; off >>= 1) s += __shfl_down(s, off, 64);
    if (lane == 0) {
        s += sb2[0];
        if (PAIRMODE == 0) {
            simout[r] = s;
        } else {
            float p = 1.0f / (1.0f + expf(-s));
            float v = laste[so[r * 2]] * p;
            atomicAdd(&newe[so[r * 2 + 1]], v);
        }
    }
}

__global__ void k_softmax(const float* __restrict__ sim, float* __restrict__ outp, int n)
{
    __shared__ float red[256];
    __shared__ float s_mx, s_sum;
    const int tid = threadIdx.x;
    float mx = -1e30f;
    for (int i = tid; i < n; i += 256) mx = fmaxf(mx, sim[i]);
    red[tid] = mx; __syncthreads();
    for (int off = 128; off > 0; off >>= 1) {
        if (tid < off) red[tid] = fmaxf(red[tid], red[tid + off]);
        __syncthreads();
    }
    if (tid == 0) s_mx = red[0];
    __syncthreads();
    const float mxv = s_mx;
    float sum = 0;
    for (int i = tid; i < n; i += 256) sum += expf(sim[i] - mxv);
    red[tid] = sum; __syncthreads();
    for (int off = 128; off > 0; off >>= 1) {
        if (tid < off) red[tid] += red[tid + off];
        __syncthreads();
    }
    if (tid == 0) s_sum = red[0];
    __syncthreads();
    const float inv = 1.0f / s_sum;
    for (int i = tid; i < n; i += 256) {
        float v = expf(sim[i] - mxv) * inv;
        outp[i] = v / fmaxf(v, 1.0f);
    }
}

__global__ void k_zero(float* p, int n)
{
    int i = blockIdx.x * blockDim.x + threadIdx.x;
    if (i < n) p[i] = 0.0f;
}

__global__ void k_clampstore(const float* __restrict__ ne, float* __restrict__ outp, int n)
{
    int i = blockIdx.x * blockDim.x + threadIdx.x;
    if (i < n) { float v = ne[i]; outp[i] = v / fmaxf(v, 1.0f); }
}

__global__ void k_final(const float* __restrict__ probs, const float* __restrict__ hlog,
                        float* __restrict__ out, int n)
{
    int i = blockIdx.x * blockDim.x + threadIdx.x;
    if (i >= n) return;
    float l0 = hlog[0], l1 = hlog[1], l2 = hlog[2];
    float m = fmaxf(l0, fmaxf(l1, l2));
    float e0 = expf(l0 - m), e1 = expf(l1 - m), e2 = expf(l2 - m);
    float inv = 1.0f / (e0 + e1 + e2);
    out[i] = (e0 * probs[i] + e1 * probs[n + i] + e2 * probs[2 * n + i]) * inv;
}

// ---------------------------------------------------------------------------
extern "C" void kernel_launch(void* const* d_in, const int* in_sizes, int n_in,
                              void* d_out, int out_size, void* d_ws, size_t ws_size,
                              hipStream_t stream)
{
    const size_t WS_NEED = 142871040;  // 136.3 MiB
    if (ws_size < WS_NEED) return;

    const float* para  = (const float*)d_in[0];
    const float* q     = (const float*)d_in[1];
    const float* qwh   = (const float*)d_in[2];
    const float* stW1  = (const float*)d_in[3];
    const float* stb1  = (const float*)d_in[4];
    const float* stW2  = (const float*)d_in[5];
    const float* stb2  = (const float*)d_in[6];
    const float* mW1   = (const float*)d_in[7];
    const float* mb1   = (const float*)d_in[8];
    const float* mW2   = (const float*)d_in[9];
    const float* mb2   = (const float*)d_in[10];
    const float* pW1   = (const float*)d_in[11];
    const float* pb1   = (const float*)d_in[12];
    const float* pW2   = (const float*)d_in[13];
    const float* pb2   = (const float*)d_in[14];
    const float* simW1 = (const float*)d_in[15];
    const float* simb1 = (const float*)d_in[16];
    const float* simW2 = (const float*)d_in[17];
    const float* simb2 = (const float*)d_in[18];
    const float* hW1   = (const float*)d_in[19];
    const float* hb1   = (const float*)d_in[20];
    const float* hW2   = (const float*)d_in[21];
    const float* hb2   = (const float*)d_in[22];
    const int*   mpos  = (const int*)d_in[23];
    const int*   mid   = (const int*)d_in[24];
    const int*   ppos  = (const int*)d_in[25];
    const int*   pso   = (const int*)d_in[26];

    // ---- workspace layout ----
    ushort* P1h  = (ushort*)d_ws;          // 15,360,000 (EM -> sub_feat -> pair_emb)
    ushort* P1l  = P1h  + 15360000;
    ushort* HIDh = P1l  + 15360000;        //  7,680,000 (hidden; H256 fp32 overlay)
    ushort* HIDl = HIDh + 7680000;
    ushort* Eh   = HIDl + 7680000;         //  7,680,000 (Wfold tmp -> ent_emb -> obj)
    ushort* El   = Eh   + 7680000;
    ushort* mW1Th = El    + 7680000;
    ushort* mW1Tl = mW1Th + 1179648;
    ushort* mW2Th = mW1Tl + 1179648;
    ushort* mW2Tl = mW2Th + 589824;
    ushort* WfTh  = mW2Tl + 589824;        // [768][2304] folded
    ushort* WfTl  = WfTh  + 1769472;
    ushort* pW2Th = WfTl  + 1769472;
    ushort* pW2Tl = pW2Th + 589824;
    ushort* W1sTh0 = pW2Tl + 589824;       // 196,608 each x3 steps
    ushort* W1sTl0 = W1sTh0 + 3 * 196608;
    float*  W1s   = (float*)(W1sTl0 + 3 * 196608);  // 196,608
    float*  simb  = W1s  + 196608;         // 20,000
    float*  probs = simb + 20000;          // 30,000
    float*  newe  = probs + 30000;         // 10,000
    float*  acc3  = newe + 10000;          // 13,824 (3 x 6 x 768)
    float*  h3    = acc3 + 13824;          // 2,304
    float*  cq3   = h3   + 2304;           // 2,304
    float*  ctx3  = cq3  + 2304;           // 2,304
    float*  hacc  = ctx3 + 2304;           // 1,536 (6 x 256)
    float*  hh    = hacc + 1536;           // 256
    float*  hlog  = hh   + 256;            // 4
    float*  H256  = (float*)HIDh;          // 20000x256 fp32 overlay
    float*  Wfold = (float*)Eh;            // fp32 tmp (dead before E written)

    dim3 B256(256);
    const ushort* np = nullptr;

    // 0) weight prep
    k_fold<<<(2304 * D + 255) / 256, B256, 0, stream>>>(pW1, Wfold, 2304 * D);
    k_wt<<<dim3(48, 24), B256, 0, stream>>>(mW1, mW1Th, mW1Tl, 2 * D, D);
    k_wt<<<dim3(24, 24), B256, 0, stream>>>(mW2, mW2Th, mW2Tl, D, D);
    k_wt<<<dim3(72, 24), B256, 0, stream>>>(Wfold, WfTh, WfTl, 3 * D, D);
    k_wt<<<dim3(24, 24), B256, 0, stream>>>(pW2, pW2Th, pW2Tl, D, D);

    // 1) batched step MLPs: all 3 steps in parallel, split-K matvec
    k_mvpart<<<dim3(12, 6, 3), B256, 0, stream>>>(q, 0, stW1, acc3, D, D, 6);
    k_biasact<<<dim3(3, 3), B256, 0, stream>>>(acc3, stb1, h3, D, 6, 1);
    k_mvpart<<<dim3(12, 6, 3), B256, 0, stream>>>(h3, D, stW2, acc3, D, D, 6);
    k_biasact<<<dim3(3, 3), B256, 0, stream>>>(acc3, stb2, cq3, D, 6, 0);
    k_ctx3<<<3, B256, 0, stream>>>(cq3, qwh, ctx3);
    for (int t = 0; t < NSTEP; ++t) {
        k_scalew<<<768, 256, 0, stream>>>(ctx3 + (size_t)t * D, simW1, W1s, D * 256);
        k_wt<<<dim3(24, 8), B256, 0, stream>>>(W1s, W1sTh0 + t * 196608,
                                               W1sTl0 + t * 196608, D, 256);
    }

    // 2) entity mention means -> P1 planes
    k_entmean<<<NENT, 256, 0, stream>>>(para, mpos, mid, MMENT, P1h, P1l);

    // 3) ent_emb
    gemm_m<0, 1, 1><<<942, B256, 0, stream>>>(P1h, P1l, nullptr, nullptr, 0, 0,
        np, np, np, np, mW1Th, mW1Tl, mb1, nullptr, HIDh, HIDl, NENT, D, 2 * D, 6);
    gemm_m<0, 0, 1><<<942, B256, 0, stream>>>(HIDh, HIDl, nullptr, nullptr, 0, 0,
        np, np, np, np, mW2Th, mW2Tl, mb2, nullptr, Eh, El, NENT, D, D, 6);

    // 4) step 0: sim on entities -> probs[0]
    gemm_m<0, 1, 0><<<314, B256, 0, stream>>>(Eh, El, nullptr, nullptr, 0, 0,
        np, np, np, np, W1sTh0, W1sTl0, simb1, H256, nullptr, nullptr, NENT, 256, D, 2);
    k_rowdot<0><<<NENT / 4, 256, 0, stream>>>(H256, simW2, simb2, NENT, simb,
                                              nullptr, nullptr, nullptr);
    k_softmax<<<1, 256, 0, stream>>>(simb, probs, NENT);

    // 5) pair pipeline, chunked; folded pair W1 (K=2304)
    for (int c = 0; c < NPAIR / CHUNK; ++c) {
        const int* pp = ppos + (size_t)c * CHUNK * 5;
        ushort* sdh = P1h + (size_t)c * CHUNK * D;
        ushort* sdl = P1l + (size_t)c * CHUNK * D;
        gemm_m<1, 1, 1><<<942, B256, 0, stream>>>(np, np, para, pp, 1, 2,
            np, np, np, np, mW1Th, mW1Tl, mb1, nullptr, HIDh, HIDl, CHUNK, D, 2 * D, 6);
        gemm_m<0, 0, 1><<<942, B256, 0, stream>>>(HIDh, HIDl, nullptr, nullptr, 0, 0,
            np, np, np, np, mW2Th, mW2Tl, mb2, nullptr, sdh, sdl, CHUNK, D, D, 6);
        gemm_m<1, 1, 1><<<942, B256, 0, stream>>>(np, np, para, pp, 3, 4,
            np, np, np, np, mW1Th, mW1Tl, mb1, nullptr, HIDh, HIDl, CHUNK, D, 2 * D, 6);
        gemm_m<0, 0, 1><<<942, B256, 0, stream>>>(HIDh, HIDl, nullptr, nullptr, 0, 0,
            np, np, np, np, mW2Th, mW2Tl, mb2, nullptr, Eh, El, CHUNK, D, D, 6);
        gemm_m<2, 1, 1><<<942, B256, 0, stream>>>(np, np, nullptr, nullptr, 0, 0,
            sdh, sdl, Eh, El, WfTh, WfTl, pb1, nullptr, HIDh, HIDl, CHUNK, D, 3 * D, 6);
        gemm_m<0, 0, 1><<<942, B256, 0, stream>>>(HIDh, HIDl, nullptr, nullptr, 0, 0,
            np, np, np, np, pW2Th, pW2Tl, pb2, nullptr, sdh, sdl, CHUNK, D, D, 6);
    }

    // 6) steps 1,2: sim on pairs + scatter-propagate
    for (int t = 1; t < NSTEP; ++t) {
        gemm_m<0, 1, 0><<<626, B256, 0, stream>>>(P1h, P1l, nullptr, nullptr, 0, 0,
            np, np, np, np, W1sTh0 + t * 196608, W1sTl0 + t * 196608, simb1,
            H256, nullptr, nullptr, NPAIR, 256, D, 2);
        k_zero<<<40, 256, 0, stream>>>(newe, NENT);
        k_rowdot<1><<<NPAIR / 4, 256, 0, stream>>>(H256, simW2, simb2, NPAIR, nullptr,
                                                   probs + (t - 1) * NENT, pso, newe);
        k_clampstore<<<40, 256, 0, stream>>>(newe, probs + t * NENT, NENT);
    }

    // 7) hop attention (split-K) + final mix
    k_mvpart<<<dim3(4, 6, 1), B256, 0, stream>>>(q, 0, hW1, hacc, D, 256, 6);
    k_biasact<<<dim3(1, 1), B256, 0, stream>>>(hacc, hb1, hh, 256, 6, 1);
    k_dot3<<<1, B256, 0, stream>>>(hh, hW2, hb2, hlog);
    k_final<<<40, 256, 0, stream>>>(probs, hlog, (float*)d_out, NENT);
}

// Round 11
// 1278.217 us; speedup vs baseline: 3.4954x; 1.2500x over previous
//
#include <hip/hip_runtime.h>
#include <math.h>

// ---------------------------------------------------------------------------
#define D 768
#define NPARA 32
#define LPARA 512
#define LQ 32
#define NENT 10000
#define MMENT 30000
#define NPAIR 20000
#define NSTEP 3

using bf16x8 = __attribute__((ext_vector_type(8))) short;
using f32x4  = __attribute__((ext_vector_type(4))) float;

__device__ __forceinline__ float geluf(float x) {
    return 0.5f * x * (1.0f + erff(x * 0.70710678118654752f));
}
__device__ __forceinline__ float bf2f(ushort h) {
    union { unsigned u; float f; } v; v.u = ((unsigned)h) << 16; return v.f;
}
// round-to-nearest-even fp32 -> bf16
__device__ __forceinline__ ushort bfrne(float x) {
    union { float f; unsigned u; } v; v.f = x;
    unsigned r = (v.u + 0x7FFF + ((v.u >> 16) & 1)) >> 16;
    return (ushort)r;
}

// ---------------------------------------------------------------------------
// Single-plane bf16 MFMA GEMM. 64x128 tile, A+B LDS (XOR-swizzled), register
// prefetch of next A and B tiles, band-major XCD swizzle.
// MODE 0: A = bf16 plane [M][K]
// MODE 1: A row r = concat(para[p,t1,:], para[p,t2,:]) fp32 gather, K=1536
// MODE 2: A row r, sections {S, O, S*O} from bf16 feats, K=2304 (folded W1)
// B: pre-transposed bf16 weights WT[N][K]. OUTP 0: fp32 C; 1: bf16 C.
// ---------------------------------------------------------------------------
#define BM 64
#define BN 128

__device__ __forceinline__ int ldso(int row, int kb) {   // ushort index
    return row * 64 + (((kb) ^ ((row & 7) << 4)) >> 1);
}

template <int MODE, int ACT, int OUTP>
__global__ __launch_bounds__(256, 5) void gemm_m(
    const ushort* __restrict__ Ah,
    const float* __restrict__ para, const int* __restrict__ ppos, int c1, int c2,
    const ushort* __restrict__ Sh, const ushort* __restrict__ Oh,
    const ushort* __restrict__ Bh, const float* __restrict__ bias,
    float* __restrict__ Cf, ushort* __restrict__ Ch,
    int M, int N, int K, int nby)
{
    __shared__ ushort sA[BM * 64];   //  8 KB
    __shared__ ushort sB[BN * 64];   // 16 KB

    const int nwg = gridDim.x;
    const int q = nwg >> 3, r = nwg & 7;
    const int xcd = blockIdx.x & 7, idx = blockIdx.x >> 3;
    const int wgid = (xcd < r) ? xcd * (q + 1) + idx
                               : r * (q + 1) + (xcd - r) * q + idx;
    const int m0 = (wgid / nby) * BM;
    const int n0 = (wgid % nby) * BN;

    const int tid = threadIdx.x;
    const int lane = tid & 63;
    const int wv = tid >> 6;
    const int wr = (wv >> 1) * 32;
    const int wc = (wv & 1) * 64;
    const int ln = lane & 15;
    const int kg = lane >> 4;

    f32x4 acc[2][4];
#pragma unroll
    for (int i = 0; i < 2; ++i)
#pragma unroll
        for (int j = 0; j < 4; ++j)
#pragma unroll
            for (int e = 0; e < 4; ++e) acc[i][j][e] = 0.0f;

    const int arow = tid >> 2, aq = tid & 3;   // A: 4 thr/row, 16 ushort each
    const int brow = tid >> 1, bq = tid & 1;   // B: 2 thr/row, 32 ushort each
    const int gm = m0 + arow;
    const bool ok = gm < M;

    int baseL = 0, baseR = 0;
    if (MODE == 1 && ok) {
        int p = ppos[gm * 5];
        baseL = (p * LPARA + ppos[gm * 5 + c1]) * D;
        baseR = (p * LPARA + ppos[gm * 5 + c2]) * D;
    }

    bf16x8 pa[2];     // MODE 0 prefetch
    float4 pf[4];     // MODE 1 prefetch (16 fp32)
    ushort4 ps[8];    // MODE 2 prefetch (S and/or O quads)
    bf16x8 pb[4];     // B prefetch (32 ushorts)

    auto prefA = [&](int kt) {
        if (MODE == 0) {
            if (ok) {
                const ushort* g = Ah + (size_t)gm * K + kt + aq * 16;
                pa[0] = *(const bf16x8*)g;
                pa[1] = *(const bf16x8*)(g + 8);
            } else {
#pragma unroll
                for (int i = 0; i < 2; ++i)
#pragma unroll
                    for (int z = 0; z < 8; ++z) pa[i][z] = 0;
            }
        } else if (MODE == 1) {
            const int kb = kt + aq * 16;            // never crosses D boundary
            const int gb = (kb < D) ? (baseL + kb) : (baseR + kb - D);
#pragma unroll
            for (int j = 0; j < 4; ++j)
                pf[j] = ok ? *(const float4*)(para + gb + j * 4)
                           : make_float4(0.f, 0.f, 0.f, 0.f);
        } else {
            const int sec = kt / D;
            const size_t rb = (size_t)gm * D + (kt - sec * D) + aq * 16;
            if (ok) {
                if (sec == 0) {
#pragma unroll
                    for (int j = 0; j < 4; ++j)
                        ps[j] = *(const ushort4*)(Sh + rb + j * 4);
                } else if (sec == 1) {
#pragma unroll
                    for (int j = 0; j < 4; ++j)
                        ps[j] = *(const ushort4*)(Oh + rb + j * 4);
                } else {
#pragma unroll
                    for (int j = 0; j < 4; ++j) {
                        ps[j]     = *(const ushort4*)(Sh + rb + j * 4);
                        ps[4 + j] = *(const ushort4*)(Oh + rb + j * 4);
                    }
                }
            }
        }
    };

    auto prefB = [&](int kt) {
        const ushort* g = Bh + (size_t)(n0 + brow) * K + kt + bq * 32;
#pragma unroll
        for (int i = 0; i < 4; ++i)
            pb[i] = *(const bf16x8*)(g + i * 8);
    };

    auto storeAB = [&](int kt) {
        if (MODE == 0) {
            int o0 = ldso(arow, aq * 32), o1 = ldso(arow, aq * 32 + 16);
            *(bf16x8*)&sA[o0] = pa[0];
            *(bf16x8*)&sA[o1] = pa[1];
        } else if (MODE == 1) {
#pragma unroll
            for (int j = 0; j < 4; ++j) {
                ushort4 h;
                h.x = bfrne(pf[j].x); h.y = bfrne(pf[j].y);
                h.z = bfrne(pf[j].z); h.w = bfrne(pf[j].w);
                *(ushort4*)&sA[ldso(arow, aq * 32 + j * 8)] = h;
            }
        } else {
            const int sec = kt / D;
#pragma unroll
            for (int j = 0; j < 4; ++j) {
                ushort4 h;
                if (ok) {
                    if (sec < 2) {
                        h = ps[j];
                    } else {
                        h.x = bfrne(bf2f(ps[j].x) * bf2f(ps[4 + j].x));
                        h.y = bfrne(bf2f(ps[j].y) * bf2f(ps[4 + j].y));
                        h.z = bfrne(bf2f(ps[j].z) * bf2f(ps[4 + j].z));
                        h.w = bfrne(bf2f(ps[j].w) * bf2f(ps[4 + j].w));
                    }
                } else {
                    h.x = h.y = h.z = h.w = 0;
                }
                *(ushort4*)&sA[ldso(arow, aq * 32 + j * 8)] = h;
            }
        }
#pragma unroll
        for (int i = 0; i < 4; ++i)
            *(bf16x8*)&sB[ldso(brow, bq * 64 + i * 16)] = pb[i];
    };

    prefA(0);
    prefB(0);

    for (int kt = 0; kt < K; kt += 64) {
        if (kt > 0) __syncthreads();
        storeAB(kt);
        __syncthreads();

        const int ktn = kt + 64;
        if (ktn < K) { prefA(ktn); prefB(ktn); }

#pragma unroll
        for (int ks = 0; ks < 2; ++ks) {
            bf16x8 fb[4];
#pragma unroll
            for (int ni = 0; ni < 4; ++ni)
                fb[ni] = *(const bf16x8*)&sB[ldso(wc + ni * 16 + ln, ks * 64 + kg * 16)];
#pragma unroll
            for (int mi = 0; mi < 2; ++mi) {
                bf16x8 fa = *(const bf16x8*)&sA[ldso(wr + mi * 16 + ln, ks * 64 + kg * 16)];
#pragma unroll
                for (int ni = 0; ni < 4; ++ni)
                    acc[mi][ni] = __builtin_amdgcn_mfma_f32_16x16x32_bf16(
                        fa, fb[ni], acc[mi][ni], 0, 0, 0);
            }
        }
    }

    // epilogue: row = (lane>>4)*4+reg, col = lane&15
#pragma unroll
    for (int mi = 0; mi < 2; ++mi)
#pragma unroll
        for (int ni = 0; ni < 4; ++ni) {
            int col = n0 + wc + ni * 16 + ln;
            f32x4 a = acc[mi][ni];
#pragma unroll
            for (int j = 0; j < 4; ++j) {
                int row = m0 + wr + mi * 16 + kg * 4 + j;
                if (row < M) {
                    float v = a[j] + bias[col];
                    if (ACT == 1) v = geluf(v);
                    if (OUTP == 0) Cf[(size_t)row * N + col] = v;
                    else           Ch[(size_t)row * N + col] = bfrne(v);
                }
            }
        }
}

// ---------------------------------------------------------------------------
// Weight transpose: W[K][N] fp32 -> WT[N][K] bf16 (RNE)
__global__ __launch_bounds__(256) void k_wt(const float* __restrict__ W,
                                            ushort* __restrict__ WTh, int K, int N)
{
    __shared__ float t[32][33];
    const int k0 = blockIdx.x * 32, n0 = blockIdx.y * 32;
    const int c = threadIdx.x & 31, r8 = threadIdx.x >> 5;
#pragma unroll
    for (int i = 0; i < 4; ++i) {
        int r = r8 + i * 8;
        t[r][c] = W[(size_t)(k0 + r) * N + n0 + c];
    }
    __syncthreads();
#pragma unroll
    for (int i = 0; i < 4; ++i) {
        int r = r8 + i * 8;
        WTh[(size_t)(n0 + r) * K + k0 + c] = bfrne(t[c][r]);
    }
}

// folded pair W1: Wf[2304][768] from pW1[3072][768]
__global__ void k_fold(const float* __restrict__ pW1, float* __restrict__ Wf, int n)
{
    int i = blockIdx.x * blockDim.x + threadIdx.x;
    if (i >= n) return;
    int row = i / D;
    float v;
    if (row < D)            v = pW1[i] - pW1[i + 1536 * D];
    else if (row < 2 * D)   v = pW1[i] + pW1[i + 768 * D];
    else                    v = pW1[i + 768 * D];
    Wf[i] = v;
}

__global__ __launch_bounds__(256) void k_entmean(
    const float* __restrict__ para, const int* __restrict__ mpos,
    const int* __restrict__ mid, int M, ushort* __restrict__ oh)
{
    __shared__ int sb[2];
    const int e = blockIdx.x;
    if (threadIdx.x < 2) {
        int target = e + threadIdx.x;
        int lo = 0, hi = M;
        while (lo < hi) {
            int md = (lo + hi) >> 1;
            if (mid[md] < target) lo = md + 1; else hi = md;
        }
        sb[threadIdx.x] = lo;
    }
    __syncthreads();
    const int lo = sb[0], hi = sb[1];
    const int tid = threadIdx.x;
    float a0 = 0, a1 = 0, a2 = 0, b0 = 0, b1 = 0, b2 = 0;
    for (int m = lo; m < hi; ++m) {
        int p = mpos[m * 3], t1 = mpos[m * 3 + 1], t2 = mpos[m * 3 + 2];
        const float* L = para + (size_t)(p * LPARA + t1) * D;
        const float* R = para + (size_t)(p * LPARA + t2) * D;
        a0 += L[tid]; a1 += L[tid + 256]; a2 += L[tid + 512];
        b0 += R[tid]; b1 += R[tid + 256]; b2 += R[tid + 512];
    }
    const float inv = (hi > lo) ? 1.0f / (float)(hi - lo) : 0.0f;
    size_t base = (size_t)e * (2 * D);
    float vals[6] = { a0 * inv, a1 * inv, a2 * inv, b0 * inv, b1 * inv, b2 * inv };
    int offs[6] = { tid, tid + 256, tid + 512, D + tid, D + tid + 256, D + tid + 512 };
#pragma unroll
    for (int i = 0; i < 6; ++i) oh[base + offs[i]] = bfrne(vals[i]);
}

// ---------------------------------------------------------------------------
// Batched split-K matvec (deterministic). grid (N/64, nks, T).
__global__ __launch_bounds__(256) void k_mvpart(
    const float* __restrict__ x, int xstride,
    const float* __restrict__ W, float* __restrict__ acc, int K, int N, int nks)
{
    const int t = blockIdx.z;
    const float* xt = x + (size_t)t * xstride;
    const float* Wt = W + (size_t)t * K * N;
    const int jj = threadIdx.x & 63;
    const int kq = threadIdx.x >> 6;
    const int j = blockIdx.x * 64 + jj;
    const int kchunk = K / (nks * 4);
    const int kbeg = (blockIdx.y * 4 + kq) * kchunk;
    float s = 0.0f;
    for (int k = kbeg; k < kbeg + kchunk; ++k)
        s = fmaf(xt[k], Wt[(size_t)k * N + j], s);
    __shared__ float red[256];
    red[threadIdx.x] = s;
    __syncthreads();
    if (kq == 0) {
        float v = red[jj] + red[64 + jj] + red[128 + jj] + red[192 + jj];
        acc[((size_t)(t * nks) + blockIdx.y) * N + j] = v;
    }
}

__global__ void k_biasact(const float* __restrict__ acc, const float* __restrict__ b,
                          float* __restrict__ out, int N, int nks, int act)
{
    const int t = blockIdx.y;
    const int j = blockIdx.x * 256 + threadIdx.x;
    if (j >= N) return;
    float s = 0.0f;
    for (int i = 0; i < nks; ++i) s += acc[((size_t)(t * nks) + i) * N + j];
    s += b[(size_t)t * N + j];
    if (act) s = geluf(s);
    out[(size_t)t * N + j] = s;
}

__global__ void k_dot3(const float* __restrict__ x, const float* __restrict__ W,
                       const float* __restrict__ b, float* __restrict__ out)
{
    int j = threadIdx.x >> 6, lane = threadIdx.x & 63;
    if (j >= 3) return;
    float s = 0.0f;
#pragma unroll
    for (int i = 0; i < 4; ++i) {
        int k = lane + i * 64;
        s += x[k] * W[k * 3 + j];
    }
    for (int off = 32; off > 0; off >>= 1) s += __shfl_down(s, off, 64);
    if (lane == 0) out[j] = s + b[j];
}

__global__ void k_ctx3(const float* __restrict__ cq3, const float* __restrict__ qwh,
                       float* __restrict__ ctx3)
{
    const float* cq = cq3 + (size_t)blockIdx.x * D;
    float* ctx = ctx3 + (size_t)blockIdx.x * D;
    __shared__ float red[256];
    __shared__ float dist[LQ];
    const int tid = threadIdx.x;
    const int l = tid >> 3, part = tid & 7;
    float s = 0.0f;
    for (int d = part; d < D; d += 8) s += cq[d] * qwh[l * D + d];
    red[tid] = s;
    __syncthreads();
    if (part == 0) {
        float v = 0;
        for (int i = 0; i < 8; ++i) v += red[l * 8 + i];
        dist[l] = v;
    }
    __syncthreads();
    if (tid == 0) {
        float mx = -1e30f;
        for (int i = 0; i < LQ; ++i) mx = fmaxf(mx, dist[i]);
        float sm = 0;
        for (int i = 0; i < LQ; ++i) { float e = expf(dist[i] - mx); dist[i] = e; sm += e; }
        float inv = 1.0f / sm;
        for (int i = 0; i < LQ; ++i) dist[i] *= inv;
    }
    __syncthreads();
    for (int d = tid; d < D; d += 256) {
        float v = 0;
#pragma unroll
        for (int l2 = 0; l2 < LQ; ++l2) v += dist[l2] * qwh[l2 * D + d];
        ctx[d] = v + cq[d];
    }
}

__global__ void k_scalew(const float* __restrict__ ctx, const float* __restrict__ w1,
                         float* __restrict__ o, int n)
{
    int i = blockIdx.x * 256 + threadIdx.x;
    if (i < n) o[i] = ctx[i >> 8] * w1[i];
}

template <int PAIRMODE>
__global__ void k_rowdot(const float* __restrict__ H, const float* __restrict__ w2,
                         const float* __restrict__ sb2, int Nr,
                         float* __restrict__ simout,
                         const float* __restrict__ laste, const int* __restrict__ so,
                         float* __restrict__ newe)
{
    int r = blockIdx.x * 4 + (threadIdx.x >> 6);
    int lane = threadIdx.x & 63;
    if (r >= Nr) return;
    float s = 0.0f;
#pragma unroll
    for (int i = 0; i < 4; ++i)
        s += H[(size_t)r * 256 + lane + i * 64] * w2[lane + i * 64];
    for (int off = 32; off > 0; off >>= 1) s += __shfl_down(s, off, 64);
    if (lane == 0) {
        s += sb2[0];
        if (PAIRMODE == 0) {
            simout[r] = s;
        } else {
            float p = 1.0f / (1.0f + expf(-s));
            float v = laste[so[r * 2]] * p;
            atomicAdd(&newe[so[r * 2 + 1]], v);
        }
    }
}

__global__ void k_softmax(const float* __restrict__ sim, float* __restrict__ outp, int n)
{
    __shared__ float red[256];
    __shared__ float s_mx, s_sum;
    const int tid = threadIdx.x;
    float mx = -1e30f;
    for (int i = tid; i < n; i += 256) mx = fmaxf(mx, sim[i]);
    red[tid] = mx; __syncthreads();
    for (int off = 128; off > 0; off >>= 1) {
        if (tid < off) red[tid] = fmaxf(red[tid], red[tid + off]);
        __syncthreads();
    }
    if (tid == 0) s_mx = red[0];
    __syncthreads();
    const float mxv = s_mx;
    float sum = 0;
    for (int i = tid; i < n; i += 256) sum += expf(sim[i] - mxv);
    red[tid] = sum; __syncthreads();
    for (int off = 128; off > 0; off >>= 1) {
        if (tid < off) red[tid] += red[tid + off];
        __syncthreads();
    }
    if (tid == 0) s_sum = red[0];
    __syncthreads();
    const float inv = 1.0f / s_sum;
    for (int i = tid; i < n; i += 256) {
        float v = expf(sim[i] - mxv) * inv;
        outp[i] = v / fmaxf(v, 1.0f);
    }
}

__global__ void k_zero(float* p, int n)
{
    int i = blockIdx.x * blockDim.x + threadIdx.x;
    if (i < n) p[i] = 0.0f;
}

__global__ void k_clampstore(const float* __restrict__ ne, float* __restrict__ outp, int n)
{
    int i = blockIdx.x * blockDim.x + threadIdx.x;
    if (i < n) { float v = ne[i]; outp[i] = v / fmaxf(v, 1.0f); }
}

__global__ void k_final(const float* __restrict__ probs, const float* __restrict__ hlog,
                        float* __restrict__ out, int n)
{
    int i = blockIdx.x * blockDim.x + threadIdx.x;
    if (i >= n) return;
    float l0 = hlog[0], l1 = hlog[1], l2 = hlog[2];
    float m = fmaxf(l0, fmaxf(l1, l2));
    float e0 = expf(l0 - m), e1 = expf(l1 - m), e2 = expf(l2 - m);
    float inv = 1.0f / (e0 + e1 + e2);
    out[i] = (e0 * probs[i] + e1 * probs[n + i] + e2 * probs[2 * n + i]) * inv;
}

// ---------------------------------------------------------------------------
extern "C" void kernel_launch(void* const* d_in, const int* in_sizes, int n_in,
                              void* d_out, int out_size, void* d_ws, size_t ws_size,
                              hipStream_t stream)
{
    const size_t WS_NEED = 118073744;  // 112.6 MiB
    if (ws_size < WS_NEED) return;

    const float* para  = (const float*)d_in[0];
    const float* q     = (const float*)d_in[1];
    const float* qwh   = (const float*)d_in[2];
    const float* stW1  = (const float*)d_in[3];
    const float* stb1  = (const float*)d_in[4];
    const float* stW2  = (const float*)d_in[5];
    const float* stb2  = (const float*)d_in[6];
    const float* mW1   = (const float*)d_in[7];
    const float* mb1   = (const float*)d_in[8];
    const float* mW2   = (const float*)d_in[9];
    const float* mb2   = (const float*)d_in[10];
    const float* pW1   = (const float*)d_in[11];
    const float* pb1   = (const float*)d_in[12];
    const float* pW2   = (const float*)d_in[13];
    const float* pb2   = (const float*)d_in[14];
    const float* simW1 = (const float*)d_in[15];
    const float* simb1 = (const float*)d_in[16];
    const float* simW2 = (const float*)d_in[17];
    const float* simb2 = (const float*)d_in[18];
    const float* hW1   = (const float*)d_in[19];
    const float* hb1   = (const float*)d_in[20];
    const float* hW2   = (const float*)d_in[21];
    const float* hb2   = (const float*)d_in[22];
    const int*   mpos  = (const int*)d_in[23];
    const int*   mid   = (const int*)d_in[24];
    const int*   ppos  = (const int*)d_in[25];
    const int*   pso   = (const int*)d_in[26];

    // ---- workspace layout (single bf16 planes) ----
    ushort* P1   = (ushort*)d_ws;          // 15,360,000 (EM -> sub_feat -> pair_emb)
    ushort* HID  = P1  + 15360000;         // 15,360,000 (hidden 20000x768; H256 overlay)
    ushort* OBJ  = HID + 15360000;         // 15,360,000 (Wfold tmp -> obj_feat)
    ushort* E    = OBJ + 15360000;         //  7,680,000 (ent_emb)
    ushort* mW1T = E    + 7680000;         //  1,179,648
    ushort* mW2T = mW1T + 1179648;         //    589,824
    ushort* WfT  = mW2T + 589824;          //  1,769,472 ([768][2304] folded)
    ushort* pW2T = WfT  + 1769472;         //    589,824
    ushort* W1sT0 = pW2T + 589824;         //    589,824 (3 x 196,608)
    float*  W1s   = (float*)(W1sT0 + 589824);  // 196,608
    float*  simb  = W1s  + 196608;         // 20,000
    float*  probs = simb + 20000;          // 30,000
    float*  newe  = probs + 30000;         // 10,000
    float*  acc3  = newe + 10000;          // 13,824
    float*  h3    = acc3 + 13824;          // 2,304
    float*  cq3   = h3   + 2304;           // 2,304
    float*  ctx3  = cq3  + 2304;           // 2,304
    float*  hacc  = ctx3 + 2304;           // 1,536
    float*  hh    = hacc + 1536;           // 256
    float*  hlog  = hh   + 256;            // 4
    float*  H256  = (float*)HID;           // 20000x256 fp32 overlay (HID dead then)
    float*  Wfold = (float*)OBJ;           // fp32 tmp (dead before OBJ written)

    dim3 B256(256);
    const ushort* np = nullptr;

    // 0) weight prep
    k_fold<<<(2304 * D + 255) / 256, B256, 0, stream>>>(pW1, Wfold, 2304 * D);
    k_wt<<<dim3(48, 24), B256, 0, stream>>>(mW1, mW1T, 2 * D, D);
    k_wt<<<dim3(24, 24), B256, 0, stream>>>(mW2, mW2T, D, D);
    k_wt<<<dim3(72, 24), B256, 0, stream>>>(Wfold, WfT, 3 * D, D);
    k_wt<<<dim3(24, 24), B256, 0, stream>>>(pW2, pW2T, D, D);

    // 1) batched step MLPs + ctx + scaled sim weights
    k_mvpart<<<dim3(12, 6, 3), B256, 0, stream>>>(q, 0, stW1, acc3, D, D, 6);
    k_biasact<<<dim3(3, 3), B256, 0, stream>>>(acc3, stb1, h3, D, 6, 1);
    k_mvpart<<<dim3(12, 6, 3), B256, 0, stream>>>(h3, D, stW2, acc3, D, D, 6);
    k_biasact<<<dim3(3, 3), B256, 0, stream>>>(acc3, stb2, cq3, D, 6, 0);
    k_ctx3<<<3, B256, 0, stream>>>(cq3, qwh, ctx3);
    for (int t = 0; t < NSTEP; ++t) {
        k_scalew<<<768, 256, 0, stream>>>(ctx3 + (size_t)t * D, simW1, W1s, D * 256);
        k_wt<<<dim3(24, 8), B256, 0, stream>>>(W1s, W1sT0 + t * 196608, D, 256);
    }

    // 2) entity mention means -> P1 (10000 x 1536 bf16)
    k_entmean<<<NENT, 256, 0, stream>>>(para, mpos, mid, MMENT, P1);

    // 3) ent_emb: gelu(EM@mW1) -> HID; HID@mW2 -> E
    gemm_m<0, 1, 1><<<942, B256, 0, stream>>>(P1, nullptr, nullptr, 0, 0, np, np,
        mW1T, mb1, nullptr, HID, NENT, D, 2 * D, 6);
    gemm_m<0, 0, 1><<<942, B256, 0, stream>>>(HID, nullptr, nullptr, 0, 0, np, np,
        mW2T, mb2, nullptr, E, NENT, D, D, 6);

    // 4) step 0: sim on entities -> probs[0]  (H256 overlays HID, ent hidden dead)
    gemm_m<0, 1, 0><<<314, B256, 0, stream>>>(E, nullptr, nullptr, 0, 0, np, np,
        W1sT0, simb1, H256, nullptr, NENT, 256, D, 2);
    k_rowdot<0><<<NENT / 4, 256, 0, stream>>>(H256, simW2, simb2, NENT, simb,
                                              nullptr, nullptr, nullptr);
    k_softmax<<<1, 256, 0, stream>>>(simb, probs, NENT);

    // 5) pair pipeline, full 20000 rows per launch (no chunking)
    gemm_m<1, 1, 1><<<1878, B256, 0, stream>>>(np, para, ppos, 1, 2, np, np,
        mW1T, mb1, nullptr, HID, NPAIR, D, 2 * D, 6);
    gemm_m<0, 0, 1><<<1878, B256, 0, stream>>>(HID, nullptr, nullptr, 0, 0, np, np,
        mW2T, mb2, nullptr, P1, NPAIR, D, D, 6);
    gemm_m<1, 1, 1><<<1878, B256, 0, stream>>>(np, para, ppos, 3, 4, np, np,
        mW1T, mb1, nullptr, HID, NPAIR, D, 2 * D, 6);
    gemm_m<0, 0, 1><<<1878, B256, 0, stream>>>(HID, nullptr, nullptr, 0, 0, np, np,
        mW2T, mb2, nullptr, OBJ, NPAIR, D, D, 6);
    gemm_m<2, 1, 1><<<1878, B256, 0, stream>>>(np, nullptr, nullptr, 0, 0, P1, OBJ,
        WfT, pb1, nullptr, HID, NPAIR, D, 3 * D, 6);
    gemm_m<0, 0, 1><<<1878, B256, 0, stream>>>(HID, nullptr, nullptr, 0, 0, np, np,
        pW2T, pb2, nullptr, P1, NPAIR, D, D, 6);

    // 6) steps 1,2: sim on pairs + scatter-propagate (H256 overlays HID)
    for (int t = 1; t < NSTEP; ++t) {
        gemm_m<0, 1, 0><<<626, B256, 0, stream>>>(P1, nullptr, nullptr, 0, 0, np, np,
            W1sT0 + t * 196608, simb1, H256, nullptr, NPAIR, 256, D, 2);
        k_zero<<<40, 256, 0, stream>>>(newe, NENT);
        k_rowdot<1><<<NPAIR / 4, 256, 0, stream>>>(H256, simW2, simb2, NPAIR, nullptr,
                                                   probs + (t - 1) * NENT, pso, newe);
        k_clampstore<<<40, 256, 0, stream>>>(newe, probs + t * NENT, NENT);
    }

    // 7) hop attention + final mix
    k_mvpart<<<dim3(4, 6, 1), B256, 0, stream>>>(q, 0, hW1, hacc, D, 256, 6);
    k_biasact<<<dim3(1, 1), B256, 0, stream>>>(hacc, hb1, hh, 256, 6, 1);
    k_dot3<<<1, B256, 0, stream>>>(hh, hW2, hb2, hlog);
    k_final<<<40, 256, 0, stream>>>(probs, hlog, (float*)d_out, NENT);
}

// Round 12
// 814.868 us; speedup vs baseline: 5.4830x; 1.5686x over previous
//
#include <hip/hip_runtime.h>
#include <math.h>

// ---------------------------------------------------------------------------
#define D 768
#define NPARA 32
#define LPARA 512
#define LQ 32
#define NENT 10000
#define MMENT 30000
#define NPAIR 20000
#define NSTEP 3

using bf16x8 = __attribute__((ext_vector_type(8))) short;
using f32x4  = __attribute__((ext_vector_type(4))) float;

__device__ __forceinline__ float geluf(float x) {
    return 0.5f * x * (1.0f + erff(x * 0.70710678118654752f));
}
__device__ __forceinline__ float bf2f(ushort h) {
    union { unsigned u; float f; } v; v.u = ((unsigned)h) << 16; return v.f;
}
// round-to-nearest-even fp32 -> bf16
__device__ __forceinline__ ushort bfrne(float x) {
    union { float f; unsigned u; } v; v.f = x;
    unsigned r = (v.u + 0x7FFF + ((v.u >> 16) & 1)) >> 16;
    return (ushort)r;
}

// ---------------------------------------------------------------------------
// Single-plane bf16 MFMA GEMM. 64x128 tile, A+B LDS (XOR-swizzled), register
// prefetch of next A and B tiles, band-major XCD swizzle.
// MODE 0: A = bf16 plane [M][K]
// MODE 1: A row r = concat(para[p,t1,:], para[p,t2,:]) fp32 gather, K=1536
// MODE 2: A row r, sections {S, O, S*O} from bf16 feats, K=2304 (folded W1)
// B: pre-transposed bf16 weights WT[N][K]. OUTP 0: fp32 C; 1: bf16 C.
// NOTE: launch_bounds (256,4): (256,5) capped regs at ~102 -> prefetch arrays
// spilled to scratch (R11: WRITE_SIZE 570MB vs 30MB design, VGPR 48).
// ---------------------------------------------------------------------------
#define BM 64
#define BN 128

__device__ __forceinline__ int ldso(int row, int kb) {   // ushort index
    return row * 64 + (((kb) ^ ((row & 7) << 4)) >> 1);
}

template <int MODE, int ACT, int OUTP>
__global__ __launch_bounds__(256, 4) void gemm_m(
    const ushort* __restrict__ Ah,
    const float* __restrict__ para, const int* __restrict__ ppos, int c1, int c2,
    const ushort* __restrict__ Sh, const ushort* __restrict__ Oh,
    const ushort* __restrict__ Bh, const float* __restrict__ bias,
    float* __restrict__ Cf, ushort* __restrict__ Ch,
    int M, int N, int K, int nby)
{
    __shared__ ushort sA[BM * 64];   //  8 KB
    __shared__ ushort sB[BN * 64];   // 16 KB

    const int nwg = gridDim.x;
    const int q = nwg >> 3, r = nwg & 7;
    const int xcd = blockIdx.x & 7, idx = blockIdx.x >> 3;
    const int wgid = (xcd < r) ? xcd * (q + 1) + idx
                               : r * (q + 1) + (xcd - r) * q + idx;
    const int m0 = (wgid / nby) * BM;
    const int n0 = (wgid % nby) * BN;

    const int tid = threadIdx.x;
    const int lane = tid & 63;
    const int wv = tid >> 6;
    const int wr = (wv >> 1) * 32;
    const int wc = (wv & 1) * 64;
    const int ln = lane & 15;
    const int kg = lane >> 4;

    f32x4 acc[2][4];
#pragma unroll
    for (int i = 0; i < 2; ++i)
#pragma unroll
        for (int j = 0; j < 4; ++j)
#pragma unroll
            for (int e = 0; e < 4; ++e) acc[i][j][e] = 0.0f;

    const int arow = tid >> 2, aq = tid & 3;   // A: 4 thr/row, 16 ushort each
    const int brow = tid >> 1, bq = tid & 1;   // B: 2 thr/row, 32 ushort each
    const int gm = m0 + arow;
    const bool ok = gm < M;

    int baseL = 0, baseR = 0;
    if (MODE == 1 && ok) {
        int p = ppos[gm * 5];
        baseL = (p * LPARA + ppos[gm * 5 + c1]) * D;
        baseR = (p * LPARA + ppos[gm * 5 + c2]) * D;
    }

    bf16x8 pa[2];     // MODE 0 prefetch
    float4 pf[4];     // MODE 1 prefetch (16 fp32)
    ushort4 ps[8];    // MODE 2 prefetch (S and/or O quads)
    bf16x8 pb[4];     // B prefetch (32 ushorts)

    auto prefA = [&](int kt) {
        if (MODE == 0) {
            if (ok) {
                const ushort* g = Ah + (size_t)gm * K + kt + aq * 16;
                pa[0] = *(const bf16x8*)g;
                pa[1] = *(const bf16x8*)(g + 8);
            } else {
#pragma unroll
                for (int i = 0; i < 2; ++i)
#pragma unroll
                    for (int z = 0; z < 8; ++z) pa[i][z] = 0;
            }
        } else if (MODE == 1) {
            const int kb = kt + aq * 16;            // never crosses D boundary
            const int gb = (kb < D) ? (baseL + kb) : (baseR + kb - D);
#pragma unroll
            for (int j = 0; j < 4; ++j)
                pf[j] = ok ? *(const float4*)(para + gb + j * 4)
                           : make_float4(0.f, 0.f, 0.f, 0.f);
        } else {
            const int sec = kt / D;
            const size_t rb = (size_t)gm * D + (kt - sec * D) + aq * 16;
            if (ok) {
                if (sec == 0) {
#pragma unroll
                    for (int j = 0; j < 4; ++j)
                        ps[j] = *(const ushort4*)(Sh + rb + j * 4);
                } else if (sec == 1) {
#pragma unroll
                    for (int j = 0; j < 4; ++j)
                        ps[j] = *(const ushort4*)(Oh + rb + j * 4);
                } else {
#pragma unroll
                    for (int j = 0; j < 4; ++j) {
                        ps[j]     = *(const ushort4*)(Sh + rb + j * 4);
                        ps[4 + j] = *(const ushort4*)(Oh + rb + j * 4);
                    }
                }
            }
        }
    };

    auto prefB = [&](int kt) {
        const ushort* g = Bh + (size_t)(n0 + brow) * K + kt + bq * 32;
#pragma unroll
        for (int i = 0; i < 4; ++i)
            pb[i] = *(const bf16x8*)(g + i * 8);
    };

    auto storeAB = [&](int kt) {
        if (MODE == 0) {
            int o0 = ldso(arow, aq * 32), o1 = ldso(arow, aq * 32 + 16);
            *(bf16x8*)&sA[o0] = pa[0];
            *(bf16x8*)&sA[o1] = pa[1];
        } else if (MODE == 1) {
#pragma unroll
            for (int j = 0; j < 4; ++j) {
                ushort4 h;
                h.x = bfrne(pf[j].x); h.y = bfrne(pf[j].y);
                h.z = bfrne(pf[j].z); h.w = bfrne(pf[j].w);
                *(ushort4*)&sA[ldso(arow, aq * 32 + j * 8)] = h;
            }
        } else {
            const int sec = kt / D;
#pragma unroll
            for (int j = 0; j < 4; ++j) {
                ushort4 h;
                if (ok) {
                    if (sec < 2) {
                        h = ps[j];
                    } else {
                        h.x = bfrne(bf2f(ps[j].x) * bf2f(ps[4 + j].x));
                        h.y = bfrne(bf2f(ps[j].y) * bf2f(ps[4 + j].y));
                        h.z = bfrne(bf2f(ps[j].z) * bf2f(ps[4 + j].z));
                        h.w = bfrne(bf2f(ps[j].w) * bf2f(ps[4 + j].w));
                    }
                } else {
                    h.x = h.y = h.z = h.w = 0;
                }
                *(ushort4*)&sA[ldso(arow, aq * 32 + j * 8)] = h;
            }
        }
#pragma unroll
        for (int i = 0; i < 4; ++i)
            *(bf16x8*)&sB[ldso(brow, bq * 64 + i * 16)] = pb[i];
    };

    prefA(0);
    prefB(0);

    for (int kt = 0; kt < K; kt += 64) {
        if (kt > 0) __syncthreads();
        storeAB(kt);
        __syncthreads();

        const int ktn = kt + 64;
        if (ktn < K) { prefA(ktn); prefB(ktn); }

#pragma unroll
        for (int ks = 0; ks < 2; ++ks) {
            bf16x8 fb[4];
#pragma unroll
            for (int ni = 0; ni < 4; ++ni)
                fb[ni] = *(const bf16x8*)&sB[ldso(wc + ni * 16 + ln, ks * 64 + kg * 16)];
#pragma unroll
            for (int mi = 0; mi < 2; ++mi) {
                bf16x8 fa = *(const bf16x8*)&sA[ldso(wr + mi * 16 + ln, ks * 64 + kg * 16)];
#pragma unroll
                for (int ni = 0; ni < 4; ++ni)
                    acc[mi][ni] = __builtin_amdgcn_mfma_f32_16x16x32_bf16(
                        fa, fb[ni], acc[mi][ni], 0, 0, 0);
            }
        }
    }

    // epilogue: row = (lane>>4)*4+reg, col = lane&15
#pragma unroll
    for (int mi = 0; mi < 2; ++mi)
#pragma unroll
        for (int ni = 0; ni < 4; ++ni) {
            int col = n0 + wc + ni * 16 + ln;
            f32x4 a = acc[mi][ni];
#pragma unroll
            for (int j = 0; j < 4; ++j) {
                int row = m0 + wr + mi * 16 + kg * 4 + j;
                if (row < M) {
                    float v = a[j] + bias[col];
                    if (ACT == 1) v = geluf(v);
                    if (OUTP == 0) Cf[(size_t)row * N + col] = v;
                    else           Ch[(size_t)row * N + col] = bfrne(v);
                }
            }
        }
}

// ---------------------------------------------------------------------------
// Weight transpose: W[K][N] fp32 -> WT[N][K] bf16 (RNE)
__global__ __launch_bounds__(256) void k_wt(const float* __restrict__ W,
                                            ushort* __restrict__ WTh, int K, int N)
{
    __shared__ float t[32][33];
    const int k0 = blockIdx.x * 32, n0 = blockIdx.y * 32;
    const int c = threadIdx.x & 31, r8 = threadIdx.x >> 5;
#pragma unroll
    for (int i = 0; i < 4; ++i) {
        int r = r8 + i * 8;
        t[r][c] = W[(size_t)(k0 + r) * N + n0 + c];
    }
    __syncthreads();
#pragma unroll
    for (int i = 0; i < 4; ++i) {
        int r = r8 + i * 8;
        WTh[(size_t)(n0 + r) * K + k0 + c] = bfrne(t[c][r]);
    }
}

// folded pair W1: Wf[2304][768] from pW1[3072][768]
__global__ void k_fold(const float* __restrict__ pW1, float* __restrict__ Wf, int n)
{
    int i = blockIdx.x * blockDim.x + threadIdx.x;
    if (i >= n) return;
    int row = i / D;
    float v;
    if (row < D)            v = pW1[i] - pW1[i + 1536 * D];
    else if (row < 2 * D)   v = pW1[i] + pW1[i + 768 * D];
    else                    v = pW1[i + 768 * D];
    Wf[i] = v;
}

__global__ __launch_bounds__(256) void k_entmean(
    const float* __restrict__ para, const int* __restrict__ mpos,
    const int* __restrict__ mid, int M, ushort* __restrict__ oh)
{
    __shared__ int sb[2];
    const int e = blockIdx.x;
    if (threadIdx.x < 2) {
        int target = e + threadIdx.x;
        int lo = 0, hi = M;
        while (lo < hi) {
            int md = (lo + hi) >> 1;
            if (mid[md] < target) lo = md + 1; else hi = md;
        }
        sb[threadIdx.x] = lo;
    }
    __syncthreads();
    const int lo = sb[0], hi = sb[1];
    const int tid = threadIdx.x;
    float a0 = 0, a1 = 0, a2 = 0, b0 = 0, b1 = 0, b2 = 0;
    for (int m = lo; m < hi; ++m) {
        int p = mpos[m * 3], t1 = mpos[m * 3 + 1], t2 = mpos[m * 3 + 2];
        const float* L = para + (size_t)(p * LPARA + t1) * D;
        const float* R = para + (size_t)(p * LPARA + t2) * D;
        a0 += L[tid]; a1 += L[tid + 256]; a2 += L[tid + 512];
        b0 += R[tid]; b1 += R[tid + 256]; b2 += R[tid + 512];
    }
    const float inv = (hi > lo) ? 1.0f / (float)(hi - lo) : 0.0f;
    size_t base = (size_t)e * (2 * D);
    float vals[6] = { a0 * inv, a1 * inv, a2 * inv, b0 * inv, b1 * inv, b2 * inv };
    int offs[6] = { tid, tid + 256, tid + 512, D + tid, D + tid + 256, D + tid + 512 };
#pragma unroll
    for (int i = 0; i < 6; ++i) oh[base + offs[i]] = bfrne(vals[i]);
}

// ---------------------------------------------------------------------------
// Batched split-K matvec (deterministic). grid (N/64, nks, T).
__global__ __launch_bounds__(256) void k_mvpart(
    const float* __restrict__ x, int xstride,
    const float* __restrict__ W, float* __restrict__ acc, int K, int N, int nks)
{
    const int t = blockIdx.z;
    const float* xt = x + (size_t)t * xstride;
    const float* Wt = W + (size_t)t * K * N;
    const int jj = threadIdx.x & 63;
    const int kq = threadIdx.x >> 6;
    const int j = blockIdx.x * 64 + jj;
    const int kchunk = K / (nks * 4);
    const int kbeg = (blockIdx.y * 4 + kq) * kchunk;
    float s = 0.0f;
    for (int k = kbeg; k < kbeg + kchunk; ++k)
        s = fmaf(xt[k], Wt[(size_t)k * N + j], s);
    __shared__ float red[256];
    red[threadIdx.x] = s;
    __syncthreads();
    if (kq == 0) {
        float v = red[jj] + red[64 + jj] + red[128 + jj] + red[192 + jj];
        acc[((size_t)(t * nks) + blockIdx.y) * N + j] = v;
    }
}

__global__ void k_biasact(const float* __restrict__ acc, const float* __restrict__ b,
                          float* __restrict__ out, int N, int nks, int act)
{
    const int t = blockIdx.y;
    const int j = blockIdx.x * 256 + threadIdx.x;
    if (j >= N) return;
    float s = 0.0f;
    for (int i = 0; i < nks; ++i) s += acc[((size_t)(t * nks) + i) * N + j];
    s += b[(size_t)t * N + j];
    if (act) s = geluf(s);
    out[(size_t)t * N + j] = s;
}

__global__ void k_dot3(const float* __restrict__ x, const float* __restrict__ W,
                       const float* __restrict__ b, float* __restrict__ out)
{
    int j = threadIdx.x >> 6, lane = threadIdx.x & 63;
    if (j >= 3) return;
    float s = 0.0f;
#pragma unroll
    for (int i = 0; i < 4; ++i) {
        int k = lane + i * 64;
        s += x[k] * W[k * 3 + j];
    }
    for (int off = 32; off > 0; off >>= 1) s += __shfl_down(s, off, 64);
    if (lane == 0) out[j] = s + b[j];
}

__global__ void k_ctx3(const float* __restrict__ cq3, const float* __restrict__ qwh,
                       float* __restrict__ ctx3)
{
    const float* cq = cq3 + (size_t)blockIdx.x * D;
    float* ctx = ctx3 + (size_t)blockIdx.x * D;
    __shared__ float red[256];
    __shared__ float dist[LQ];
    const int tid = threadIdx.x;
    const int l = tid >> 3, part = tid & 7;
    float s = 0.0f;
    for (int d = part; d < D; d += 8) s += cq[d] * qwh[l * D + d];
    red[tid] = s;
    __syncthreads();
    if (part == 0) {
        float v = 0;
        for (int i = 0; i < 8; ++i) v += red[l * 8 + i];
        dist[l] = v;
    }
    __syncthreads();
    if (tid == 0) {
        float mx = -1e30f;
        for (int i = 0; i < LQ; ++i) mx = fmaxf(mx, dist[i]);
        float sm = 0;
        for (int i = 0; i < LQ; ++i) { float e = expf(dist[i] - mx); dist[i] = e; sm += e; }
        float inv = 1.0f / sm;
        for (int i = 0; i < LQ; ++i) dist[i] *= inv;
    }
    __syncthreads();
    for (int d = tid; d < D; d += 256) {
        float v = 0;
#pragma unroll
        for (int l2 = 0; l2 < LQ; ++l2) v += dist[l2] * qwh[l2 * D + d];
        ctx[d] = v + cq[d];
    }
}

__global__ void k_scalew(const float* __restrict__ ctx, const float* __restrict__ w1,
                         float* __restrict__ o, int n)
{
    int i = blockIdx.x * 256 + threadIdx.x;
    if (i < n) o[i] = ctx[i >> 8] * w1[i];
}

template <int PAIRMODE>
__global__ void k_rowdot(const float* __restrict__ H, const float* __restrict__ w2,
                         const float* __restrict__ sb2, int Nr,
                         float* __restrict__ simout,
                         const float* __restrict__ laste, const int* __restrict__ so,
                         float* __restrict__ newe)
{
    int r = blockIdx.x * 4 + (threadIdx.x >> 6);
    int lane = threadIdx.x & 63;
    if (r >= Nr) return;
    float s = 0.0f;
#pragma unroll
    for (int i = 0; i < 4; ++i)
        s += H[(size_t)r * 256 + lane + i * 64] * w2[lane + i * 64];
    for (int off = 32; off > 0; off >>= 1) s += __shfl_down(s, off, 64);
    if (lane == 0) {
        s += sb2[0];
        if (PAIRMODE == 0) {
            simout[r] = s;
        } else {
            float p = 1.0f / (1.0f + expf(-s));
            float v = laste[so[r * 2]] * p;
            atomicAdd(&newe[so[r * 2 + 1]], v);
        }
    }
}

__global__ void k_softmax(const float* __restrict__ sim, float* __restrict__ outp, int n)
{
    __shared__ float red[256];
    __shared__ float s_mx, s_sum;
    const int tid = threadIdx.x;
    float mx = -1e30f;
    for (int i = tid; i < n; i += 256) mx = fmaxf(mx, sim[i]);
    red[tid] = mx; __syncthreads();
    for (int off = 128; off > 0; off >>= 1) {
        if (tid < off) red[tid] = fmaxf(red[tid], red[tid + off]);
        __syncthreads();
    }
    if (tid == 0) s_mx = red[0];
    __syncthreads();
    const float mxv = s_mx;
    float sum = 0;
    for (int i = tid; i < n; i += 256) sum += expf(sim[i] - mxv);
    red[tid] = sum; __syncthreads();
    for (int off = 128; off > 0; off >>= 1) {
        if (tid < off) red[tid] += red[tid + off];
        __syncthreads();
    }
    if (tid == 0) s_sum = red[0];
    __syncthreads();
    const float inv = 1.0f / s_sum;
    for (int i = tid; i < n; i += 256) {
        float v = expf(sim[i] - mxv) * inv;
        outp[i] = v / fmaxf(v, 1.0f);
    }
}

__global__ void k_zero(float* p, int n)
{
    int i = blockIdx.x * blockDim.x + threadIdx.x;
    if (i < n) p[i] = 0.0f;
}

__global__ void k_clampstore(const float* __restrict__ ne, float* __restrict__ outp, int n)
{
    int i = blockIdx.x * blockDim.x + threadIdx.x;
    if (i < n) { float v = ne[i]; outp[i] = v / fmaxf(v, 1.0f); }
}

__global__ void k_final(const float* __restrict__ probs, const float* __restrict__ hlog,
                        float* __restrict__ out, int n)
{
    int i = blockIdx.x * blockDim.x + threadIdx.x;
    if (i >= n) return;
    float l0 = hlog[0], l1 = hlog[1], l2 = hlog[2];
    float m = fmaxf(l0, fmaxf(l1, l2));
    float e0 = expf(l0 - m), e1 = expf(l1 - m), e2 = expf(l2 - m);
    float inv = 1.0f / (e0 + e1 + e2);
    out[i] = (e0 * probs[i] + e1 * probs[n + i] + e2 * probs[2 * n + i]) * inv;
}

// ---------------------------------------------------------------------------
extern "C" void kernel_launch(void* const* d_in, const int* in_sizes, int n_in,
                              void* d_out, int out_size, void* d_ws, size_t ws_size,
                              hipStream_t stream)
{
    const size_t WS_NEED = 118073744;  // 112.6 MiB
    if (ws_size < WS_NEED) return;

    const float* para  = (const float*)d_in[0];
    const float* q     = (const float*)d_in[1];
    const float* qwh   = (const float*)d_in[2];
    const float* stW1  = (const float*)d_in[3];
    const float* stb1  = (const float*)d_in[4];
    const float* stW2  = (const float*)d_in[5];
    const float* stb2  = (const float*)d_in[6];
    const float* mW1   = (const float*)d_in[7];
    const float* mb1   = (const float*)d_in[8];
    const float* mW2   = (const float*)d_in[9];
    const float* mb2   = (const float*)d_in[10];
    const float* pW1   = (const float*)d_in[11];
    const float* pb1   = (const float*)d_in[12];
    const float* pW2   = (const float*)d_in[13];
    const float* pb2   = (const float*)d_in[14];
    const float* simW1 = (const float*)d_in[15];
    const float* simb1 = (const float*)d_in[16];
    const float* simW2 = (const float*)d_in[17];
    const float* simb2 = (const float*)d_in[18];
    const float* hW1   = (const float*)d_in[19];
    const float* hb1   = (const float*)d_in[20];
    const float* hW2   = (const float*)d_in[21];
    const float* hb2   = (const float*)d_in[22];
    const int*   mpos  = (const int*)d_in[23];
    const int*   mid   = (const int*)d_in[24];
    const int*   ppos  = (const int*)d_in[25];
    const int*   pso   = (const int*)d_in[26];

    // ---- workspace layout (single bf16 planes) ----
    ushort* P1   = (ushort*)d_ws;          // 15,360,000 (EM -> sub_feat -> pair_emb)
    ushort* HID  = P1  + 15360000;         // 15,360,000 (hidden 20000x768; H256 overlay)
    ushort* OBJ  = HID + 15360000;         // 15,360,000 (Wfold tmp -> obj_feat)
    ushort* E    = OBJ + 15360000;         //  7,680,000 (ent_emb)
    ushort* mW1T = E    + 7680000;         //  1,179,648
    ushort* mW2T = mW1T + 1179648;         //    589,824
    ushort* WfT  = mW2T + 589824;          //  1,769,472 ([768][2304] folded)
    ushort* pW2T = WfT  + 1769472;         //    589,824
    ushort* W1sT0 = pW2T + 589824;         //    589,824 (3 x 196,608)
    float*  W1s   = (float*)(W1sT0 + 589824);  // 196,608
    float*  simb  = W1s  + 196608;         // 20,000
    float*  probs = simb + 20000;          // 30,000
    float*  newe  = probs + 30000;         // 10,000
    float*  acc3  = newe + 10000;          // 13,824
    float*  h3    = acc3 + 13824;          // 2,304
    float*  cq3   = h3   + 2304;           // 2,304
    float*  ctx3  = cq3  + 2304;           // 2,304
    float*  hacc  = ctx3 + 2304;           // 1,536
    float*  hh    = hacc + 1536;           // 256
    float*  hlog  = hh   + 256;            // 4
    float*  H256  = (float*)HID;           // 20000x256 fp32 overlay (HID dead then)
    float*  Wfold = (float*)OBJ;           // fp32 tmp (dead before OBJ written)

    dim3 B256(256);
    const ushort* np = nullptr;

    // 0) weight prep
    k_fold<<<(2304 * D + 255) / 256, B256, 0, stream>>>(pW1, Wfold, 2304 * D);
    k_wt<<<dim3(48, 24), B256, 0, stream>>>(mW1, mW1T, 2 * D, D);
    k_wt<<<dim3(24, 24), B256, 0, stream>>>(mW2, mW2T, D, D);
    k_wt<<<dim3(72, 24), B256, 0, stream>>>(Wfold, WfT, 3 * D, D);
    k_wt<<<dim3(24, 24), B256, 0, stream>>>(pW2, pW2T, D, D);

    // 1) batched step MLPs + ctx + scaled sim weights
    k_mvpart<<<dim3(12, 6, 3), B256, 0, stream>>>(q, 0, stW1, acc3, D, D, 6);
    k_biasact<<<dim3(3, 3), B256, 0, stream>>>(acc3, stb1, h3, D, 6, 1);
    k_mvpart<<<dim3(12, 6, 3), B256, 0, stream>>>(h3, D, stW2, acc3, D, D, 6);
    k_biasact<<<dim3(3, 3), B256, 0, stream>>>(acc3, stb2, cq3, D, 6, 0);
    k_ctx3<<<3, B256, 0, stream>>>(cq3, qwh, ctx3);
    for (int t = 0; t < NSTEP; ++t) {
        k_scalew<<<768, 256, 0, stream>>>(ctx3 + (size_t)t * D, simW1, W1s, D * 256);
        k_wt<<<dim3(24, 8), B256, 0, stream>>>(W1s, W1sT0 + t * 196608, D, 256);
    }

    // 2) entity mention means -> P1 (10000 x 1536 bf16)
    k_entmean<<<NENT, 256, 0, stream>>>(para, mpos, mid, MMENT, P1);

    // 3) ent_emb: gelu(EM@mW1) -> HID; HID@mW2 -> E
    gemm_m<0, 1, 1><<<942, B256, 0, stream>>>(P1, nullptr, nullptr, 0, 0, np, np,
        mW1T, mb1, nullptr, HID, NENT, D, 2 * D, 6);
    gemm_m<0, 0, 1><<<942, B256, 0, stream>>>(HID, nullptr, nullptr, 0, 0, np, np,
        mW2T, mb2, nullptr, E, NENT, D, D, 6);

    // 4) step 0: sim on entities -> probs[0]  (H256 overlays HID, ent hidden dead)
    gemm_m<0, 1, 0><<<314, B256, 0, stream>>>(E, nullptr, nullptr, 0, 0, np, np,
        W1sT0, simb1, H256, nullptr, NENT, 256, D, 2);
    k_rowdot<0><<<NENT / 4, 256, 0, stream>>>(H256, simW2, simb2, NENT, simb,
                                              nullptr, nullptr, nullptr);
    k_softmax<<<1, 256, 0, stream>>>(simb, probs, NENT);

    // 5) pair pipeline, full 20000 rows per launch (no chunking)
    gemm_m<1, 1, 1><<<1878, B256, 0, stream>>>(np, para, ppos, 1, 2, np, np,
        mW1T, mb1, nullptr, HID, NPAIR, D, 2 * D, 6);
    gemm_m<0, 0, 1><<<1878, B256, 0, stream>>>(HID, nullptr, nullptr, 0, 0, np, np,
        mW2T, mb2, nullptr, P1, NPAIR, D, D, 6);
    gemm_m<1, 1, 1><<<1878, B256, 0, stream>>>(np, para, ppos, 3, 4, np, np,
        mW1T, mb1, nullptr, HID, NPAIR, D, 2 * D, 6);
    gemm_m<0, 0, 1><<<1878, B256, 0, stream>>>(HID, nullptr, nullptr, 0, 0, np, np,
        mW2T, mb2, nullptr, OBJ, NPAIR, D, D, 6);
    gemm_m<2, 1, 1><<<1878, B256, 0, stream>>>(np, nullptr, nullptr, 0, 0, P1, OBJ,
        WfT, pb1, nullptr, HID, NPAIR, D, 3 * D, 6);
    gemm_m<0, 0, 1><<<1878, B256, 0, stream>>>(HID, nullptr, nullptr, 0, 0, np, np,
        pW2T, pb2, nullptr, P1, NPAIR, D, D, 6);

    // 6) steps 1,2: sim on pairs + scatter-propagate (H256 overlays HID)
    for (int t = 1; t < NSTEP; ++t) {
        gemm_m<0, 1, 0><<<626, B256, 0, stream>>>(P1, nullptr, nullptr, 0, 0, np, np,
            W1sT0 + t * 196608, simb1, H256, nullptr, NPAIR, 256, D, 2);
        k_zero<<<40, 256, 0, stream>>>(newe, NENT);
        k_rowdot<1><<<NPAIR / 4, 256, 0, stream>>>(H256, simW2, simb2, NPAIR, nullptr,
                                                   probs + (t - 1) * NENT, pso, newe);
        k_clampstore<<<40, 256, 0, stream>>>(newe, probs + t * NENT, NENT);
    }

    // 7) hop attention + final mix
    k_mvpart<<<dim3(4, 6, 1), B256, 0, stream>>>(q, 0, hW1, hacc, D, 256, 6);
    k_biasact<<<dim3(1, 1), B256, 0, stream>>>(hacc, hb1, hh, 256, 6, 1);
    k_dot3<<<1, B256, 0, stream>>>(hh, hW2, hb2, hlog);
    k_final<<<40, 256, 0, stream>>>(probs, hlog, (float*)d_out, NENT);
}